// Round 1
// baseline (4785.729 us; speedup 1.0000x reference)
//
#include <hip/hip_runtime.h>

// Problem constants
static constexpr int NN = 50000;   // nodes
static constexpr int NE = 800000;  // edges
static constexpr int INF = 256;
static constexpr int HF  = 128;
static constexpr int OUTF = 128;

// ---------------- degree / rsqrt ----------------
__global__ void deg_init(float* deg, int n) {
    int i = blockIdx.x * blockDim.x + threadIdx.x;
    if (i < n) deg[i] = 1.0f;  // self loop
}

__global__ void deg_count(float* deg, const int* __restrict__ dst, int e) {
    int i = blockIdx.x * blockDim.x + threadIdx.x;
    if (i < e) atomicAdd(&deg[dst[i]], 1.0f);
}

__global__ void deg_rsqrt(float* deg, int n) {
    int i = blockIdx.x * blockDim.x + threadIdx.x;
    if (i < n) deg[i] = rsqrtf(deg[i]);
}

// ---------------- generic tiled f32 GEMM ----------------
// C[M x Nstore] = A[M x K] * W[K x Nw] (+bias) (+relu); W row-major with ld=ldw.
// Cols in [Nw, Nstore) get weight 0 / bias 0 (used to zero-pad gemm4's output).
template<bool DO_BIAS, bool DO_RELU>
__global__ __launch_bounds__(256) void gemm_tile(
    const float* __restrict__ A, int lda,
    const float* __restrict__ W, int ldw, int Nw,
    const float* __restrict__ bias,
    float* __restrict__ C, int ldc, int Nstore,
    int M, int K)
{
    __shared__ float As[64][17];   // +1 pad: avoids 16-way bank conflict
    __shared__ float Bs[16][64];
    const int tid = threadIdx.x;
    const int row0 = blockIdx.x * 64;
    const int col0 = blockIdx.y * 64;
    const int tx = tid & 15, ty = tid >> 4;

    float acc[4][4] = {};

    const int ar = tid >> 2;        // 0..63
    const int ak = (tid & 3) * 4;   // 0,4,8,12
    const int bk = tid >> 4;        // 0..15
    const int bn = (tid & 15) * 4;  // 0..60

    for (int k0 = 0; k0 < K; k0 += 16) {
        const int arow = row0 + ar;
#pragma unroll
        for (int j = 0; j < 4; ++j) {
            const int kk = k0 + ak + j;
            As[ar][ak + j] = (arow < M && kk < K) ? A[(size_t)arow * lda + kk] : 0.f;
        }
        const int kk = k0 + bk;
#pragma unroll
        for (int j = 0; j < 4; ++j) {
            const int nn = col0 + bn + j;
            Bs[bk][bn + j] = (kk < K && nn < Nw) ? W[(size_t)kk * ldw + nn] : 0.f;
        }
        __syncthreads();
#pragma unroll
        for (int k = 0; k < 16; ++k) {
            const float a0 = As[ty * 4 + 0][k];
            const float a1 = As[ty * 4 + 1][k];
            const float a2 = As[ty * 4 + 2][k];
            const float a3 = As[ty * 4 + 3][k];
            const float4 b = *(const float4*)&Bs[k][tx * 4];
            acc[0][0] += a0 * b.x; acc[0][1] += a0 * b.y; acc[0][2] += a0 * b.z; acc[0][3] += a0 * b.w;
            acc[1][0] += a1 * b.x; acc[1][1] += a1 * b.y; acc[1][2] += a1 * b.z; acc[1][3] += a1 * b.w;
            acc[2][0] += a2 * b.x; acc[2][1] += a2 * b.y; acc[2][2] += a2 * b.z; acc[2][3] += a2 * b.w;
            acc[3][0] += a3 * b.x; acc[3][1] += a3 * b.y; acc[3][2] += a3 * b.z; acc[3][3] += a3 * b.w;
        }
        __syncthreads();
    }

#pragma unroll
    for (int i = 0; i < 4; ++i) {
        const int r = row0 + ty * 4 + i;
        if (r >= M) continue;
#pragma unroll
        for (int j = 0; j < 4; ++j) {
            const int c = col0 + tx * 4 + j;
            if (c >= Nstore) continue;
            float v = acc[i][j];
            if (DO_BIAS) v += (c < Nw) ? bias[c] : 0.f;
            if (DO_RELU) v = fmaxf(v, 0.f);
            C[(size_t)r * ldc + c] = v;
        }
    }
}

// ---------------- glue kernels ----------------
__global__ void fill_cat(float* cat, const float* __restrict__ rw1,
                         const float* __restrict__ action, int n) {
    int i = blockIdx.x * blockDim.x + threadIdx.x;
    if (i < n) {
        cat[(size_t)i * 130 + 128] = rw1[i];
        cat[(size_t)i * 130 + 129] = action[i];
    }
}

// out[i][:] = h[i][:] * dis[i]^2  (self-loop init), float4 over nvec4 chunks
__global__ void scale_rows(const float* __restrict__ h, float* __restrict__ out,
                           const float* __restrict__ dis, int nvec4, int ld) {
    const int row = blockIdx.x;
    const float d2 = dis[row] * dis[row];
    const float4* hs = (const float4*)(h + (size_t)row * ld);
    float4* od = (float4*)(out + (size_t)row * ld);
    for (int c = threadIdx.x; c < nvec4; c += blockDim.x) {
        float4 v = hs[c];
        v.x *= d2; v.y *= d2; v.z *= d2; v.w *= d2;
        od[c] = v;
    }
}

// one wave (64 lanes) per edge: out[dst] += h[src] * (dis[src]*dis[dst])
__global__ __launch_bounds__(256) void agg_edges(
    const float* __restrict__ h, float* __restrict__ out,
    const int* __restrict__ src, const int* __restrict__ dst,
    const float* __restrict__ dis, int e, int nvec4, int ld)
{
    const int wid = (blockIdx.x * blockDim.x + threadIdx.x) >> 6;
    const int lane = threadIdx.x & 63;
    if (wid >= e) return;
    const int s = src[wid], d = dst[wid];
    const float nrm = dis[s] * dis[d];
    const float4* hs = (const float4*)(h + (size_t)s * ld);
    float* od = out + (size_t)d * ld;
    for (int c = lane; c < nvec4; c += 64) {
        const float4 v = hs[c];
        atomicAdd(&od[4 * c + 0], v.x * nrm);
        atomicAdd(&od[4 * c + 1], v.y * nrm);
        atomicAdd(&od[4 * c + 2], v.z * nrm);
        atomicAdd(&od[4 * c + 3], v.w * nrm);
    }
}

__global__ void bias_relu256(float* buf, const float* __restrict__ bias, int total) {
    int i = blockIdx.x * blockDim.x + threadIdx.x;
    if (i < total) {
        const int c = i & 255;
        buf[i] = fmaxf(buf[i] + bias[c], 0.f);
    }
}

// hidden = mean + noise * exp(clip(logvar,-5,5)); tmp has ld 256 (mean|logvar)
__global__ void hidden_k(const float* __restrict__ tmp, const float* __restrict__ noise,
                         float* __restrict__ hid, int total) {
    int i = blockIdx.x * blockDim.x + threadIdx.x;
    if (i < total) {
        const int row = i >> 7, col = i & 127;
        const float m = tmp[(size_t)row * 256 + col];
        float lv = tmp[(size_t)row * 256 + 128 + col];
        lv = fmaxf(fminf(lv, 5.0f), -5.0f);
        hid[i] = m + noise[i] * __expf(lv) ;
    }
}

// g2 = relu(out2 + bg2); split into d_out[N*128] matrix + d_out[N*128 .. +N] value col
__global__ void epilogue_k(const float* __restrict__ out2, const float* __restrict__ bg2,
                           float* __restrict__ o, int n) {
    int i = blockIdx.x * blockDim.x + threadIdx.x;
    const int mat = n * 128;
    if (i < mat) {
        const int row = i >> 7, col = i & 127;
        o[i] = fmaxf(out2[(size_t)row * 132 + col] + bg2[col], 0.f);
    } else if (i < mat + n) {
        const int row = i - mat;
        o[mat + row] = fmaxf(out2[(size_t)row * 132 + 128] + bg2[128], 0.f);
    }
}

extern "C" void kernel_launch(void* const* d_in, const int* in_sizes, int n_in,
                              void* d_out, int out_size, void* d_ws, size_t ws_size,
                              hipStream_t stream)
{
    const float* x      = (const float*)d_in[0];
    const float* rw1    = (const float*)d_in[1];
    const float* action = (const float*)d_in[2];
    const float* noise  = (const float*)d_in[3];
    const int*   eidx   = (const int*)d_in[4];
    const float* W1     = (const float*)d_in[5];
    const float* b1     = (const float*)d_in[6];
    const float* Wg1    = (const float*)d_in[7];
    const float* bg1    = (const float*)d_in[8];
    const float* Whv    = (const float*)d_in[9];
    const float* bhv    = (const float*)d_in[10];
    const float* Wg2    = (const float*)d_in[11];
    const float* bg2    = (const float*)d_in[12];
    const int* src = eidx;
    const int* dst = eidx + NE;

    float* bufA = (float*)d_ws;                    // N*130 (cat -> hidden)
    float* bufB = bufA + (size_t)NN * 130;         // N*256 (h1 -> tmp -> out2)
    float* bufC = bufB + (size_t)NN * 256;         // N*256 (out3/x3a -> h2)
    float* dis  = bufC + (size_t)NN * 256;         // N

    const int T = 256;
    const int rowBlocks = (NN + 63) / 64;  // 782

    // degrees
    deg_init<<<(NN + T - 1) / T, T, 0, stream>>>(dis, NN);
    deg_count<<<(NE + T - 1) / T, T, 0, stream>>>(dis, dst, NE);
    deg_rsqrt<<<(NN + T - 1) / T, T, 0, stream>>>(dis, NN);

    // h = relu(x@W1+b1) -> bufA cols 0..127 (ld 130); cat cols 128,129
    gemm_tile<true, true><<<dim3(rowBlocks, 2), T, 0, stream>>>(
        x, INF, W1, HF, HF, b1, bufA, 130, 128, NN, INF);
    fill_cat<<<(NN + T - 1) / T, T, 0, stream>>>(bufA, rw1, action, NN);

    // h1 = cat @ Wg1 -> bufB (N x 256)
    gemm_tile<false, false><<<dim3(rowBlocks, 4), T, 0, stream>>>(
        bufA, 130, Wg1, 256, 256, nullptr, bufB, 256, 256, NN, 130);

    // aggregation 1: bufC = selfloop + edges, then relu(+bg1)
    scale_rows<<<NN, 64, 0, stream>>>(bufB, bufC, dis, 64, 256);
    agg_edges<<<(NE + 3) / 4, T, 0, stream>>>(bufB, bufC, src, dst, dis, NE, 64, 256);
    bias_relu256<<<((size_t)NN * 256 + T - 1) / T, T, 0, stream>>>(bufC, bg1, NN * 256);

    // tmp = relu(x3a @ Whv + bhv) -> bufB
    gemm_tile<true, true><<<dim3(rowBlocks, 4), T, 0, stream>>>(
        bufC, 256, Whv, 256, 256, bhv, bufB, 256, 256, NN, 256);

    // hidden -> bufA (ld 128)
    hidden_k<<<((size_t)NN * 128 + T - 1) / T, T, 0, stream>>>(bufB, noise, bufA, NN * 128);

    // h2 = hidden @ Wg2 -> bufC (ld 132, cols 129..131 zeroed)
    gemm_tile<false, false><<<dim3(rowBlocks, 3), T, 0, stream>>>(
        bufA, 128, Wg2, 129, 129, nullptr, bufC, 132, 132, NN, 128);

    // aggregation 2: bufB = selfloop + edges
    scale_rows<<<NN, 64, 0, stream>>>(bufC, bufB, dis, 33, 132);
    agg_edges<<<(NE + 3) / 4, T, 0, stream>>>(bufC, bufB, src, dst, dis, NE, 33, 132);

    // epilogue -> d_out
    epilogue_k<<<((size_t)NN * 129 + T - 1) / T, T, 0, stream>>>(bufB, bg2, (float*)d_out, NN);
}

// Round 2
// 869.981 us; speedup vs baseline: 5.5010x; 5.5010x over previous
//
#include <hip/hip_runtime.h>

// Problem constants
static constexpr int NN = 50000;   // nodes
static constexpr int NE = 800000;  // edges
static constexpr int INF = 256;
static constexpr int HF  = 128;

// ---------------- CSR build ----------------
__global__ void cnt_zero(int* cnt, int n) {
    int i = blockIdx.x * blockDim.x + threadIdx.x;
    if (i < n) cnt[i] = 0;
}

__global__ void cnt_count(int* cnt, const int* __restrict__ dst, int e) {
    int i = blockIdx.x * blockDim.x + threadIdx.x;
    if (i < e) atomicAdd(&cnt[dst[i]], 1);
}

// Single block of 1024: per-thread chunk sums -> block scan -> write rowptr & dis.
__global__ void scan_rowptr(const int* __restrict__ cnt, int* __restrict__ rowptr,
                            float* __restrict__ dis, int n) {
    const int T = 1024;
    const int L = (n + T - 1) / T;
    const int t = threadIdx.x;
    const int begin = t * L;
    const int end = min(begin + L, n);
    int sum = 0;
    for (int i = begin; i < end; ++i) sum += cnt[i];
    __shared__ int sdata[1024];
    sdata[t] = sum;
    __syncthreads();
    for (int off = 1; off < 1024; off <<= 1) {
        int v = (t >= off) ? sdata[t - off] : 0;
        __syncthreads();
        sdata[t] += v;
        __syncthreads();
    }
    int run = (t == 0) ? 0 : sdata[t - 1];
    if (t == 0) rowptr[0] = 0;
    for (int i = begin; i < end; ++i) {
        const int v = cnt[i];
        dis[i] = rsqrtf(1.0f + (float)v);   // degree includes self loop
        run += v;
        rowptr[i + 1] = run;
    }
}

__global__ void cursor_init(const int* __restrict__ rowptr, int* cursor, int n) {
    int i = blockIdx.x * blockDim.x + threadIdx.x;
    if (i < n) cursor[i] = rowptr[i];
}

__global__ void scatter_edges(const int* __restrict__ src, const int* __restrict__ dst,
                              int* cursor, int* __restrict__ esrc, int e) {
    int i = blockIdx.x * blockDim.x + threadIdx.x;
    if (i < e) {
        const int pos = atomicAdd(&cursor[dst[i]], 1);
        esrc[pos] = src[i];
    }
}

// ---------------- generic tiled f32 GEMM ----------------
template<bool DO_BIAS, bool DO_RELU>
__global__ __launch_bounds__(256) void gemm_tile(
    const float* __restrict__ A, int lda,
    const float* __restrict__ W, int ldw, int Nw,
    const float* __restrict__ bias,
    float* __restrict__ C, int ldc, int Nstore,
    int M, int K)
{
    __shared__ float As[64][17];
    __shared__ float Bs[16][64];
    const int tid = threadIdx.x;
    const int row0 = blockIdx.x * 64;
    const int col0 = blockIdx.y * 64;
    const int tx = tid & 15, ty = tid >> 4;

    float acc[4][4] = {};

    const int ar = tid >> 2;
    const int ak = (tid & 3) * 4;
    const int bk = tid >> 4;
    const int bn = (tid & 15) * 4;

    for (int k0 = 0; k0 < K; k0 += 16) {
        const int arow = row0 + ar;
#pragma unroll
        for (int j = 0; j < 4; ++j) {
            const int kk = k0 + ak + j;
            As[ar][ak + j] = (arow < M && kk < K) ? A[(size_t)arow * lda + kk] : 0.f;
        }
        const int kk = k0 + bk;
#pragma unroll
        for (int j = 0; j < 4; ++j) {
            const int nn = col0 + bn + j;
            Bs[bk][bn + j] = (kk < K && nn < Nw) ? W[(size_t)kk * ldw + nn] : 0.f;
        }
        __syncthreads();
#pragma unroll
        for (int k = 0; k < 16; ++k) {
            const float a0 = As[ty * 4 + 0][k];
            const float a1 = As[ty * 4 + 1][k];
            const float a2 = As[ty * 4 + 2][k];
            const float a3 = As[ty * 4 + 3][k];
            const float4 b = *(const float4*)&Bs[k][tx * 4];
            acc[0][0] += a0 * b.x; acc[0][1] += a0 * b.y; acc[0][2] += a0 * b.z; acc[0][3] += a0 * b.w;
            acc[1][0] += a1 * b.x; acc[1][1] += a1 * b.y; acc[1][2] += a1 * b.z; acc[1][3] += a1 * b.w;
            acc[2][0] += a2 * b.x; acc[2][1] += a2 * b.y; acc[2][2] += a2 * b.z; acc[2][3] += a2 * b.w;
            acc[3][0] += a3 * b.x; acc[3][1] += a3 * b.y; acc[3][2] += a3 * b.z; acc[3][3] += a3 * b.w;
        }
        __syncthreads();
    }

#pragma unroll
    for (int i = 0; i < 4; ++i) {
        const int r = row0 + ty * 4 + i;
        if (r >= M) continue;
#pragma unroll
        for (int j = 0; j < 4; ++j) {
            const int c = col0 + tx * 4 + j;
            if (c >= Nstore) continue;
            float v = acc[i][j];
            if (DO_BIAS) v += (c < Nw) ? bias[c] : 0.f;
            if (DO_RELU) v = fmaxf(v, 0.f);
            C[(size_t)r * ldc + c] = v;
        }
    }
}

// ---------------- glue kernels ----------------
__global__ void fill_cat(float* cat, const float* __restrict__ rw1,
                         const float* __restrict__ action, int n) {
    int i = blockIdx.x * blockDim.x + threadIdx.x;
    if (i < n) {
        cat[(size_t)i * 130 + 128] = rw1[i];
        cat[(size_t)i * 130 + 129] = action[i];
    }
}

__global__ void hidden_k(const float* __restrict__ tmp, const float* __restrict__ noise,
                         float* __restrict__ hid, int total) {
    int i = blockIdx.x * blockDim.x + threadIdx.x;
    if (i < total) {
        const int row = i >> 7, col = i & 127;
        const float m = tmp[(size_t)row * 256 + col];
        float lv = tmp[(size_t)row * 256 + 128 + col];
        lv = fmaxf(fminf(lv, 5.0f), -5.0f);
        hid[i] = m + noise[i] * __expf(lv);
    }
}

// ---------------- CSR gather aggregations ----------------
// agg1: out[node][0:256] = relu( selfloop + sum_edges + bg1 ). One wave/node.
__global__ __launch_bounds__(256) void agg1_csr(
    const float* __restrict__ h, float* __restrict__ out,
    const int* __restrict__ rowptr, const int* __restrict__ esrc,
    const float* __restrict__ dis, const float* __restrict__ bias, int n)
{
    const int node = (blockIdx.x * blockDim.x + threadIdx.x) >> 6;
    const int lane = threadIdx.x & 63;
    if (node >= n) return;
    const float dd = dis[node];
    const float d2 = dd * dd;
    const float4 v = *(const float4*)(h + (size_t)node * 256 + lane * 4);
    float ax = v.x * d2, ay = v.y * d2, az = v.z * d2, aw = v.w * d2;
    const int b = rowptr[node], e = rowptr[node + 1];
    int j = b;
    for (; j + 1 < e; j += 2) {
        const int s0 = esrc[j], s1 = esrc[j + 1];
        const float n0 = dis[s0] * dd, n1 = dis[s1] * dd;
        const float4 v0 = *(const float4*)(h + (size_t)s0 * 256 + lane * 4);
        const float4 v1 = *(const float4*)(h + (size_t)s1 * 256 + lane * 4);
        ax += v0.x * n0 + v1.x * n1;
        ay += v0.y * n0 + v1.y * n1;
        az += v0.z * n0 + v1.z * n1;
        aw += v0.w * n0 + v1.w * n1;
    }
    if (j < e) {
        const int s0 = esrc[j];
        const float n0 = dis[s0] * dd;
        const float4 v0 = *(const float4*)(h + (size_t)s0 * 256 + lane * 4);
        ax += v0.x * n0; ay += v0.y * n0; az += v0.z * n0; aw += v0.w * n0;
    }
    const float4 bb = *(const float4*)(bias + lane * 4);
    float4 r;
    r.x = fmaxf(ax + bb.x, 0.f);
    r.y = fmaxf(ay + bb.y, 0.f);
    r.z = fmaxf(az + bb.z, 0.f);
    r.w = fmaxf(aw + bb.w, 0.f);
    *(float4*)(out + (size_t)node * 256 + lane * 4) = r;
}

// agg2: input N x 132 (cols 129..131 are zero); fused epilogue/split to d_out.
// Lanes 0..32 each read a float4 (lane 32 covers cols 128..131, pad is zero).
__global__ __launch_bounds__(256) void agg2_csr(
    const float* __restrict__ h, float* __restrict__ o,
    const int* __restrict__ rowptr, const int* __restrict__ esrc,
    const float* __restrict__ dis, const float* __restrict__ bg2, int n)
{
    const int node = (blockIdx.x * blockDim.x + threadIdx.x) >> 6;
    const int lane = threadIdx.x & 63;
    if (node >= n || lane >= 33) return;
    const float dd = dis[node];
    const float d2 = dd * dd;
    const float4 v = *(const float4*)(h + (size_t)node * 132 + lane * 4);
    float ax = v.x * d2, ay = v.y * d2, az = v.z * d2, aw = v.w * d2;
    const int b = rowptr[node], e = rowptr[node + 1];
    int j = b;
    for (; j + 1 < e; j += 2) {
        const int s0 = esrc[j], s1 = esrc[j + 1];
        const float n0 = dis[s0] * dd, n1 = dis[s1] * dd;
        const float4 v0 = *(const float4*)(h + (size_t)s0 * 132 + lane * 4);
        const float4 v1 = *(const float4*)(h + (size_t)s1 * 132 + lane * 4);
        ax += v0.x * n0 + v1.x * n1;
        ay += v0.y * n0 + v1.y * n1;
        az += v0.z * n0 + v1.z * n1;
        aw += v0.w * n0 + v1.w * n1;
    }
    if (j < e) {
        const int s0 = esrc[j];
        const float n0 = dis[s0] * dd;
        const float4 v0 = *(const float4*)(h + (size_t)s0 * 132 + lane * 4);
        ax += v0.x * n0; ay += v0.y * n0; az += v0.z * n0; aw += v0.w * n0;
    }
    if (lane < 32) {
        const float4 bb = *(const float4*)(bg2 + lane * 4);
        float4 r;
        r.x = fmaxf(ax + bb.x, 0.f);
        r.y = fmaxf(ay + bb.y, 0.f);
        r.z = fmaxf(az + bb.z, 0.f);
        r.w = fmaxf(aw + bb.w, 0.f);
        *(float4*)(o + (size_t)node * 128 + lane * 4) = r;
    } else {
        o[(size_t)n * 128 + node] = fmaxf(ax + bg2[128], 0.f);
    }
}

extern "C" void kernel_launch(void* const* d_in, const int* in_sizes, int n_in,
                              void* d_out, int out_size, void* d_ws, size_t ws_size,
                              hipStream_t stream)
{
    const float* x      = (const float*)d_in[0];
    const float* rw1    = (const float*)d_in[1];
    const float* action = (const float*)d_in[2];
    const float* noise  = (const float*)d_in[3];
    const int*   eidx   = (const int*)d_in[4];
    const float* W1     = (const float*)d_in[5];
    const float* b1     = (const float*)d_in[6];
    const float* Wg1    = (const float*)d_in[7];
    const float* bg1    = (const float*)d_in[8];
    const float* Whv    = (const float*)d_in[9];
    const float* bhv    = (const float*)d_in[10];
    const float* Wg2    = (const float*)d_in[11];
    const float* bg2    = (const float*)d_in[12];
    const int* src = eidx;
    const int* dst = eidx + NE;

    float* bufA = (float*)d_ws;                    // N*130 (cat -> hidden)
    float* bufB = bufA + (size_t)NN * 130;         // N*256 (h1 -> tmp)
    float* bufC = bufB + (size_t)NN * 256;         // N*256 (x3a -> h2[ld132])
    float* dis  = bufC + (size_t)NN * 256;         // N
    int* cnt    = (int*)(dis + NN);                // N (then reused as cursor)
    int* rowptr = cnt + NN;                        // N+1
    int* esrc   = rowptr + NN + 1;                 // E

    const int T = 256;
    const int rowBlocks = (NN + 63) / 64;   // 782
    const int nodeWaveBlocks = (NN + 3) / 4; // 12500 (one wave per node)

    // ---- CSR build ----
    cnt_zero<<<(NN + T - 1) / T, T, 0, stream>>>(cnt, NN);
    cnt_count<<<(NE + T - 1) / T, T, 0, stream>>>(cnt, dst, NE);
    scan_rowptr<<<1, 1024, 0, stream>>>(cnt, rowptr, dis, NN);
    cursor_init<<<(NN + T - 1) / T, T, 0, stream>>>(rowptr, cnt, NN);
    scatter_edges<<<(NE + T - 1) / T, T, 0, stream>>>(src, dst, cnt, esrc, NE);

    // ---- h = relu(x@W1+b1) -> bufA cols 0..127 (ld 130); cat cols 128,129 ----
    gemm_tile<true, true><<<dim3(rowBlocks, 2), T, 0, stream>>>(
        x, INF, W1, HF, HF, b1, bufA, 130, 128, NN, INF);
    fill_cat<<<(NN + T - 1) / T, T, 0, stream>>>(bufA, rw1, action, NN);

    // ---- h1 = cat @ Wg1 -> bufB (N x 256) ----
    gemm_tile<false, false><<<dim3(rowBlocks, 4), T, 0, stream>>>(
        bufA, 130, Wg1, 256, 256, nullptr, bufB, 256, 256, NN, 130);

    // ---- aggregation 1 (gather) + bias + relu -> bufC ----
    agg1_csr<<<nodeWaveBlocks, T, 0, stream>>>(bufB, bufC, rowptr, esrc, dis, bg1, NN);

    // ---- tmp = relu(x3a @ Whv + bhv) -> bufB ----
    gemm_tile<true, true><<<dim3(rowBlocks, 4), T, 0, stream>>>(
        bufC, 256, Whv, 256, 256, bhv, bufB, 256, 256, NN, 256);

    // ---- hidden -> bufA (ld 128) ----
    hidden_k<<<((size_t)NN * 128 + T - 1) / T, T, 0, stream>>>(bufB, noise, bufA, NN * 128);

    // ---- h2 = hidden @ Wg2 -> bufC (ld 132, cols 129..131 zeroed) ----
    gemm_tile<false, false><<<dim3(rowBlocks, 3), T, 0, stream>>>(
        bufA, 128, Wg2, 129, 129, nullptr, bufC, 132, 132, NN, 128);

    // ---- aggregation 2 (gather) + fused epilogue/split -> d_out ----
    agg2_csr<<<nodeWaveBlocks, T, 0, stream>>>(bufC, (float*)d_out, rowptr, esrc, dis, bg2, NN);
}

// Round 3
// 513.259 us; speedup vs baseline: 9.3242x; 1.6950x over previous
//
#include <hip/hip_runtime.h>

static constexpr int NN = 50000;   // nodes
static constexpr int NE = 800000;  // edges

typedef __attribute__((ext_vector_type(8))) short bf16x8;
typedef __attribute__((ext_vector_type(4))) float f32x4;

__device__ __forceinline__ float bf2f(ushort u) {
    union { unsigned int i; float f; } c; c.i = ((unsigned int)u) << 16; return c.f;
}
__device__ __forceinline__ ushort f2bf(float f) {
    union { float f; unsigned int i; } c; c.f = f;
    unsigned int x = c.i;
    return (ushort)((x + 0x7FFFu + ((x >> 16) & 1u)) >> 16);
}

// ---------------- CSR build ----------------
__global__ void cnt_zero(int* cnt, int n) {
    int i = blockIdx.x * blockDim.x + threadIdx.x;
    if (i < n) cnt[i] = 0;
}

__global__ void cnt_count(int* cnt, const int* __restrict__ dst, int e) {
    int i = blockIdx.x * blockDim.x + threadIdx.x;
    if (i < e) atomicAdd(&cnt[dst[i]], 1);
}

__global__ void scan_rowptr(const int* __restrict__ cnt, int* __restrict__ rowptr,
                            float* __restrict__ dis, int n) {
    const int T = 1024;
    const int L = (n + T - 1) / T;
    const int t = threadIdx.x;
    const int begin = t * L;
    const int end = min(begin + L, n);
    int sum = 0;
    for (int i = begin; i < end; ++i) sum += cnt[i];
    __shared__ int sdata[1024];
    sdata[t] = sum;
    __syncthreads();
    for (int off = 1; off < 1024; off <<= 1) {
        int v = (t >= off) ? sdata[t - off] : 0;
        __syncthreads();
        sdata[t] += v;
        __syncthreads();
    }
    int run = (t == 0) ? 0 : sdata[t - 1];
    if (t == 0) rowptr[0] = 0;
    for (int i = begin; i < end; ++i) {
        const int v = cnt[i];
        dis[i] = rsqrtf(1.0f + (float)v);   // degree includes self loop
        run += v;
        rowptr[i + 1] = run;
    }
}

__global__ void cursor_init(const int* __restrict__ rowptr, int* cursor, int n) {
    int i = blockIdx.x * blockDim.x + threadIdx.x;
    if (i < n) cursor[i] = rowptr[i];
}

__global__ void scatter_edges(const int* __restrict__ src, const int* __restrict__ dst,
                              int* cursor, int* __restrict__ esrc, int e) {
    int i = blockIdx.x * blockDim.x + threadIdx.x;
    if (i < e) {
        const int pos = atomicAdd(&cursor[dst[i]], 1);
        esrc[pos] = src[i];
    }
}

// ---------------- prep: casts / transposes ----------------
__global__ void cast_x_k(const float* __restrict__ x, ushort* __restrict__ xb, int total8) {
    int i = blockIdx.x * blockDim.x + threadIdx.x;
    if (i >= total8) return;
    const float4 v0 = ((const float4*)x)[(size_t)i * 2];
    const float4 v1 = ((const float4*)x)[(size_t)i * 2 + 1];
    ushort4 a = make_ushort4(f2bf(v0.x), f2bf(v0.y), f2bf(v0.z), f2bf(v0.w));
    ushort4 b = make_ushort4(f2bf(v1.x), f2bf(v1.y), f2bf(v1.z), f2bf(v1.w));
    ((ushort4*)xb)[(size_t)i * 2] = a;
    ((ushort4*)xb)[(size_t)i * 2 + 1] = b;
}

// W [K x Nw] row-major f32 -> Wt [Nrows x Kp] bf16 (zero-padded)
__global__ void transpose_cast(const float* __restrict__ W, ushort* __restrict__ Wt,
                               int K, int Nw, int Kp, int Nrows) {
    int idx = blockIdx.x * blockDim.x + threadIdx.x;
    if (idx >= Nrows * Kp) return;
    const int n = idx / Kp, k = idx - n * Kp;
    Wt[idx] = (k < K && n < Nw) ? f2bf(W[(size_t)k * Nw + n]) : (ushort)0;
}

// ---------------- bf16 MFMA GEMM ----------------
// C[M x Nstore] = A[M x K]_bf16 * Wt[NwRows x K]_bf16^T (+bias)(+relu)
// Block: 256 thr = 4 waves; tile 128 rows x 64 cols; K multiple of 32.
template<bool DO_BIAS, bool DO_RELU, bool OUT_BF16>
__global__ __launch_bounds__(256) void gemm_mfma(
    const ushort* __restrict__ A, int lda, int M,
    const ushort* __restrict__ Wt, int K, int PW, int NwRows,
    const float* __restrict__ bias,
    void* __restrict__ Cout, int ldc, int Nstore)
{
    __shared__ ushort Wt_s[64 * 264];      // pitch PW = K+8 (2-way bank max)
    __shared__ ushort A_s[2][128 * 40];    // pitch 40 (2-way bank max)

    const int tid  = threadIdx.x;
    const int row0 = blockIdx.x * 128;
    const int col0 = blockIdx.y * 64;
    const int lane = tid & 63;
    const int wid  = tid >> 6;
    const int lr = lane & 15;
    const int kg = lane >> 4;

    // ---- load Wt strip (resident for whole K) ----
    const int ku8 = K >> 3;
    for (int idx = tid; idx < 64 * ku8; idx += 256) {
        const int n = idx / ku8;
        const int ku = idx - n * ku8;
        int4 v = make_int4(0, 0, 0, 0);
        const int gn = col0 + n;
        if (gn < NwRows) v = *(const int4*)(Wt + (size_t)gn * K + ku * 8);
        *(int4*)&Wt_s[n * PW + ku * 8] = v;
    }

    // ---- A staging (thread t: row t>>1, 32B chunk) ----
    const int sr = tid >> 1;
    const int so = (tid & 1) * 16;
    const bool rok = (row0 + sr) < M;
    const ushort* Ag = A + (size_t)(row0 + sr) * lda + so;

    int4 s0 = make_int4(0, 0, 0, 0), s1 = s0;
    if (rok) { s0 = *(const int4*)Ag; s1 = *(const int4*)(Ag + 8); }
    *(int4*)&A_s[0][sr * 40 + so] = s0;
    *(int4*)&A_s[0][sr * 40 + so + 8] = s1;

    f32x4 acc[2][4];
#pragma unroll
    for (int m = 0; m < 2; ++m)
#pragma unroll
        for (int n = 0; n < 4; ++n) acc[m][n] = (f32x4){0.f, 0.f, 0.f, 0.f};

    const int nk = K >> 5;
    const int abase = (wid * 32 + lr) * 40 + kg * 8;
    const int bbase = lr * PW + kg * 8;

    for (int kk = 0; kk < nk; ++kk) {
        const bool more = (kk + 1) < nk;
        if (more && rok) {   // prefetch next A tile (global) before compute
            s0 = *(const int4*)(Ag + (kk + 1) * 32);
            s1 = *(const int4*)(Ag + (kk + 1) * 32 + 8);
        }
        __syncthreads();
        const ushort* Ab = A_s[kk & 1];
        bf16x8 a0 = *(const bf16x8*)&Ab[abase];
        bf16x8 a1 = *(const bf16x8*)&Ab[abase + 16 * 40];
        const ushort* Bb = &Wt_s[kk * 32 + bbase];
        bf16x8 b0 = *(const bf16x8*)&Bb[0];
        bf16x8 b1 = *(const bf16x8*)&Bb[16 * PW];
        bf16x8 b2 = *(const bf16x8*)&Bb[32 * PW];
        bf16x8 b3 = *(const bf16x8*)&Bb[48 * PW];
        acc[0][0] = __builtin_amdgcn_mfma_f32_16x16x32_bf16(a0, b0, acc[0][0], 0, 0, 0);
        acc[0][1] = __builtin_amdgcn_mfma_f32_16x16x32_bf16(a0, b1, acc[0][1], 0, 0, 0);
        acc[0][2] = __builtin_amdgcn_mfma_f32_16x16x32_bf16(a0, b2, acc[0][2], 0, 0, 0);
        acc[0][3] = __builtin_amdgcn_mfma_f32_16x16x32_bf16(a0, b3, acc[0][3], 0, 0, 0);
        acc[1][0] = __builtin_amdgcn_mfma_f32_16x16x32_bf16(a1, b0, acc[1][0], 0, 0, 0);
        acc[1][1] = __builtin_amdgcn_mfma_f32_16x16x32_bf16(a1, b1, acc[1][1], 0, 0, 0);
        acc[1][2] = __builtin_amdgcn_mfma_f32_16x16x32_bf16(a1, b2, acc[1][2], 0, 0, 0);
        acc[1][3] = __builtin_amdgcn_mfma_f32_16x16x32_bf16(a1, b3, acc[1][3], 0, 0, 0);
        if (more) {          // write next tile after compute (T14 split)
            *(int4*)&A_s[(kk + 1) & 1][sr * 40 + so] = s0;
            *(int4*)&A_s[(kk + 1) & 1][sr * 40 + so + 8] = s1;
        }
    }

    // ---- epilogue: C/D layout col=lane&15, row=(lane>>4)*4+r ----
#pragma unroll
    for (int m = 0; m < 2; ++m) {
#pragma unroll
        for (int n = 0; n < 4; ++n) {
            const int c = col0 + n * 16 + lr;
            if (c >= Nstore) continue;
            const float bb = DO_BIAS ? bias[c] : 0.f;
            const int r0 = row0 + wid * 32 + m * 16 + kg * 4;
#pragma unroll
            for (int r = 0; r < 4; ++r) {
                const int R = r0 + r;
                if (R >= M) continue;
                float v = acc[m][n][r] + bb;
                if (DO_RELU) v = fmaxf(v, 0.f);
                if (OUT_BF16) ((ushort*)Cout)[(size_t)R * ldc + c] = f2bf(v);
                else          ((float*)Cout)[(size_t)R * ldc + c] = v;
            }
        }
    }
}

// ---------------- glue ----------------
// cat cols 128..159: rw1, action, zeros (K padded to 160)
__global__ void fill_cat_k(ushort* __restrict__ cat, const float* __restrict__ rw1,
                           const float* __restrict__ action, int n) {
    int i = blockIdx.x * blockDim.x + threadIdx.x;
    if (i >= n * 32) return;
    const int node = i >> 5, c = i & 31;
    float v = (c == 0) ? rw1[node] : (c == 1) ? action[node] : 0.f;
    cat[(size_t)node * 160 + 128 + c] = f2bf(v);
}

// hidden = mean + noise*exp(clip(logvar,-5,5)); tmp f32 ld 256 -> hidden bf16 ld 128
__global__ void hidden_k(const float* __restrict__ tmp, const float* __restrict__ noise,
                         ushort* __restrict__ hid, int total) {
    int i = blockIdx.x * blockDim.x + threadIdx.x;
    if (i >= total) return;
    const int row = i >> 7, col = i & 127;
    const float m = tmp[(size_t)row * 256 + col];
    float lv = tmp[(size_t)row * 256 + 128 + col];
    lv = fmaxf(fminf(lv, 5.0f), -5.0f);
    hid[i] = f2bf(m + noise[i] * expf(lv));
}

// ---------------- CSR gather aggregations (bf16 in, f32 accum) ----------------
__global__ __launch_bounds__(256) void agg1_bf(
    const ushort* __restrict__ h, ushort* __restrict__ out,
    const int* __restrict__ rowptr, const int* __restrict__ esrc,
    const float* __restrict__ dis, const float* __restrict__ bias, int n)
{
    const int node = (blockIdx.x * blockDim.x + threadIdx.x) >> 6;
    const int lane = threadIdx.x & 63;
    if (node >= n) return;
    const float dd = dis[node];
    const float d2 = dd * dd;
    float ax, ay, az, aw;
    {
        const ushort4 v = *(const ushort4*)(h + (size_t)node * 256 + lane * 4);
        ax = bf2f(v.x) * d2; ay = bf2f(v.y) * d2; az = bf2f(v.z) * d2; aw = bf2f(v.w) * d2;
    }
    const int b = rowptr[node], e = rowptr[node + 1];
    int j = b;
    for (; j + 1 < e; j += 2) {
        const int s0 = esrc[j], s1 = esrc[j + 1];
        const float n0 = dis[s0] * dd, n1 = dis[s1] * dd;
        const ushort4 v0 = *(const ushort4*)(h + (size_t)s0 * 256 + lane * 4);
        const ushort4 v1 = *(const ushort4*)(h + (size_t)s1 * 256 + lane * 4);
        ax += bf2f(v0.x) * n0 + bf2f(v1.x) * n1;
        ay += bf2f(v0.y) * n0 + bf2f(v1.y) * n1;
        az += bf2f(v0.z) * n0 + bf2f(v1.z) * n1;
        aw += bf2f(v0.w) * n0 + bf2f(v1.w) * n1;
    }
    if (j < e) {
        const int s0 = esrc[j];
        const float n0 = dis[s0] * dd;
        const ushort4 v0 = *(const ushort4*)(h + (size_t)s0 * 256 + lane * 4);
        ax += bf2f(v0.x) * n0; ay += bf2f(v0.y) * n0;
        az += bf2f(v0.z) * n0; aw += bf2f(v0.w) * n0;
    }
    const float4 bb = *(const float4*)(bias + lane * 4);
    ushort4 r = make_ushort4(f2bf(fmaxf(ax + bb.x, 0.f)), f2bf(fmaxf(ay + bb.y, 0.f)),
                             f2bf(fmaxf(az + bb.z, 0.f)), f2bf(fmaxf(aw + bb.w, 0.f)));
    *(ushort4*)(out + (size_t)node * 256 + lane * 4) = r;
}

// agg2: h2 bf16 ld 136 (cols 129..131 zero); fused bias/relu/split -> f32 d_out
__global__ __launch_bounds__(256) void agg2_bf(
    const ushort* __restrict__ h, float* __restrict__ o,
    const int* __restrict__ rowptr, const int* __restrict__ esrc,
    const float* __restrict__ dis, const float* __restrict__ bg2, int n)
{
    const int node = (blockIdx.x * blockDim.x + threadIdx.x) >> 6;
    const int lane = threadIdx.x & 63;
    if (node >= n || lane >= 33) return;
    const float dd = dis[node];
    const float d2 = dd * dd;
    float ax, ay, az, aw;
    {
        const ushort4 v = *(const ushort4*)(h + (size_t)node * 136 + lane * 4);
        ax = bf2f(v.x) * d2; ay = bf2f(v.y) * d2; az = bf2f(v.z) * d2; aw = bf2f(v.w) * d2;
    }
    const int b = rowptr[node], e = rowptr[node + 1];
    int j = b;
    for (; j + 1 < e; j += 2) {
        const int s0 = esrc[j], s1 = esrc[j + 1];
        const float n0 = dis[s0] * dd, n1 = dis[s1] * dd;
        const ushort4 v0 = *(const ushort4*)(h + (size_t)s0 * 136 + lane * 4);
        const ushort4 v1 = *(const ushort4*)(h + (size_t)s1 * 136 + lane * 4);
        ax += bf2f(v0.x) * n0 + bf2f(v1.x) * n1;
        ay += bf2f(v0.y) * n0 + bf2f(v1.y) * n1;
        az += bf2f(v0.z) * n0 + bf2f(v1.z) * n1;
        aw += bf2f(v0.w) * n0 + bf2f(v1.w) * n1;
    }
    if (j < e) {
        const int s0 = esrc[j];
        const float n0 = dis[s0] * dd;
        const ushort4 v0 = *(const ushort4*)(h + (size_t)s0 * 136 + lane * 4);
        ax += bf2f(v0.x) * n0; ay += bf2f(v0.y) * n0;
        az += bf2f(v0.z) * n0; aw += bf2f(v0.w) * n0;
    }
    if (lane < 32) {
        const float4 bb = *(const float4*)(bg2 + lane * 4);
        float4 r;
        r.x = fmaxf(ax + bb.x, 0.f);
        r.y = fmaxf(ay + bb.y, 0.f);
        r.z = fmaxf(az + bb.z, 0.f);
        r.w = fmaxf(aw + bb.w, 0.f);
        *(float4*)(o + (size_t)node * 128 + lane * 4) = r;
    } else {
        o[(size_t)n * 128 + node] = fmaxf(ax + bg2[128], 0.f);
    }
}

extern "C" void kernel_launch(void* const* d_in, const int* in_sizes, int n_in,
                              void* d_out, int out_size, void* d_ws, size_t ws_size,
                              hipStream_t stream)
{
    const float* x      = (const float*)d_in[0];
    const float* rw1    = (const float*)d_in[1];
    const float* action = (const float*)d_in[2];
    const float* noise  = (const float*)d_in[3];
    const int*   eidx   = (const int*)d_in[4];
    const float* W1     = (const float*)d_in[5];
    const float* b1     = (const float*)d_in[6];
    const float* Wg1    = (const float*)d_in[7];
    const float* bg1    = (const float*)d_in[8];
    const float* Whv    = (const float*)d_in[9];
    const float* bhv    = (const float*)d_in[10];
    const float* Wg2    = (const float*)d_in[11];
    const float* bg2    = (const float*)d_in[12];
    const int* src = eidx;
    const int* dst = eidx + NE;

    // Regions (u16 units), 12.8M each:
    // R0: x_bf -> tmp(lo)    R1: cat(8M) -> tmp(hi) -> h2(6.8M)
    // R2: h1 -> hidden       R3: x3a
    ushort* R0 = (ushort*)d_ws;
    ushort* R1 = R0 + 12800000;
    ushort* R2 = R1 + 12800000;
    ushort* R3 = R2 + 12800000;
    float* tmpf = (float*)R0;              // 12.8M f32 spans R0+R1
    float* dis  = (float*)(R3 + 12800000);
    int* cnt    = (int*)(dis + NN);
    int* rowptr = cnt + NN;
    int* esrc   = rowptr + NN + 4;         // padded for alignment
    ushort* Wt1  = (ushort*)(esrc + NE);   // [128][256]
    ushort* Wtg1 = Wt1 + 128 * 256;        // [256][160]
    ushort* Whvt = Wtg1 + 256 * 160;       // [256][256]
    ushort* Wg2t = Whvt + 256 * 256;       // [132][128]

    const int T = 256;
    const int gemmRows = (NN + 127) / 128;   // 391
    const int aggBlocks = (NN + 3) / 4;      // one wave per node

    // ---- prep: casts & weight transposes ----
    cast_x_k<<<(NN * 256 / 8 + T - 1) / T, T, 0, stream>>>(x, R0, NN * 32);
    transpose_cast<<<(128 * 256 + T - 1) / T, T, 0, stream>>>(W1, Wt1, 256, 128, 256, 128);
    transpose_cast<<<(256 * 160 + T - 1) / T, T, 0, stream>>>(Wg1, Wtg1, 130, 256, 160, 256);
    transpose_cast<<<(256 * 256 + T - 1) / T, T, 0, stream>>>(Whv, Whvt, 256, 256, 256, 256);
    transpose_cast<<<(132 * 128 + T - 1) / T, T, 0, stream>>>(Wg2, Wg2t, 128, 129, 128, 132);

    // ---- CSR build ----
    cnt_zero<<<(NN + T - 1) / T, T, 0, stream>>>(cnt, NN);
    cnt_count<<<(NE + T - 1) / T, T, 0, stream>>>(cnt, dst, NE);
    scan_rowptr<<<1, 1024, 0, stream>>>(cnt, rowptr, dis, NN);
    cursor_init<<<(NN + T - 1) / T, T, 0, stream>>>(rowptr, cnt, NN);
    scatter_edges<<<(NE + T - 1) / T, T, 0, stream>>>(src, dst, cnt, esrc, NE);

    // ---- gemm1: relu(x@W1+b1) -> cat bf16 (ld 160, cols 0..127) ----
    gemm_mfma<true, true, true><<<dim3(gemmRows, 2), T, 0, stream>>>(
        R0, 256, NN, Wt1, 256, 264, 128, b1, R1, 160, 128);
    fill_cat_k<<<(NN * 32 + T - 1) / T, T, 0, stream>>>(R1, rw1, action, NN);

    // ---- gemm2: cat@Wg1 -> h1 bf16 (ld 256) ----
    gemm_mfma<false, false, true><<<dim3(gemmRows, 4), T, 0, stream>>>(
        R1, 160, NN, Wtg1, 160, 168, 256, nullptr, R2, 256, 256);

    // ---- agg1 (+bg1, relu) -> x3a bf16 ----
    agg1_bf<<<aggBlocks, T, 0, stream>>>(R2, R3, rowptr, esrc, dis, bg1, NN);

    // ---- gemm3: relu(x3a@Whv+bhv) -> tmp f32 (ld 256, spans R0+R1) ----
    gemm_mfma<true, true, false><<<dim3(gemmRows, 4), T, 0, stream>>>(
        R3, 256, NN, Whvt, 256, 264, 256, bhv, tmpf, 256, 256);

    // ---- hidden (f32 math) -> bf16 (R2, ld 128) ----
    hidden_k<<<(NN * 128 + T - 1) / T, T, 0, stream>>>(tmpf, noise, R2, NN * 128);

    // ---- gemm4: hidden@Wg2 -> h2 bf16 (ld 136, cols 129..131 zero) ----
    gemm_mfma<false, false, true><<<dim3(gemmRows, 3), T, 0, stream>>>(
        R2, 128, NN, Wg2t, 128, 136, 132, nullptr, R1, 136, 132);

    // ---- agg2 (+bg2, relu, split) -> d_out ----
    agg2_bf<<<aggBlocks, T, 0, stream>>>(R1, (float*)d_out, rowptr, esrc, dis, bg2, NN);
}

// Round 4
// 414.866 us; speedup vs baseline: 11.5356x; 1.2372x over previous
//
#include <hip/hip_runtime.h>

static constexpr int NN = 50000;   // nodes
static constexpr int NE = 800000;  // edges

typedef __attribute__((ext_vector_type(8))) short bf16x8;
typedef __attribute__((ext_vector_type(4))) float f32x4;

__device__ __forceinline__ float bf2f(ushort u) {
    union { unsigned int i; float f; } c; c.i = ((unsigned int)u) << 16; return c.f;
}
__device__ __forceinline__ ushort f2bf(float f) {
    union { float f; unsigned int i; } c; c.f = f;
    unsigned int x = c.i;
    return (ushort)((x + 0x7FFFu + ((x >> 16) & 1u)) >> 16);
}

// ---------------- CSR build ----------------
__global__ void cnt_zero(int* cnt, int n) {
    int i = blockIdx.x * blockDim.x + threadIdx.x;
    if (i < n) cnt[i] = 0;
}

__global__ void cnt_count(int* cnt, const int* __restrict__ dst, int e) {
    int i = blockIdx.x * blockDim.x + threadIdx.x;
    if (i < e) atomicAdd(&cnt[dst[i]], 1);
}

// s1: per-block sums over chunks of 512 (256 thr x 2 elems)
__global__ __launch_bounds__(256) void scan_block_sums(
    const int* __restrict__ cnt, int* __restrict__ blockSums, int n)
{
    __shared__ int sdata[256];
    const int base = blockIdx.x * 512;
    const int t = threadIdx.x;
    const int i0 = base + t * 2;
    int v = 0;
    if (i0 < n) v += cnt[i0];
    if (i0 + 1 < n) v += cnt[i0 + 1];
    sdata[t] = v;
    __syncthreads();
#pragma unroll
    for (int off = 128; off > 0; off >>= 1) {
        if (t < off) sdata[t] += sdata[t + off];
        __syncthreads();
    }
    if (t == 0) blockSums[blockIdx.x] = sdata[0];
}

// s2: exclusive scan of blockSums (nb <= 256), single block of 256
__global__ __launch_bounds__(256) void scan_small(int* blockSums, int nb) {
    __shared__ int sdata[256];
    const int t = threadIdx.x;
    sdata[t] = (t < nb) ? blockSums[t] : 0;
    __syncthreads();
#pragma unroll
    for (int off = 1; off < 256; off <<= 1) {
        const int v = (t >= off) ? sdata[t - off] : 0;
        __syncthreads();
        sdata[t] += v;
        __syncthreads();
    }
    if (t < nb) blockSums[t] = (t == 0) ? 0 : sdata[t - 1];
}

// s3: write rowptr (exclusive prefix) + dis = rsqrt(1+deg); rowptr[n] = E.
__global__ __launch_bounds__(256) void scan_write(
    const int* __restrict__ cnt, const int* __restrict__ blockOffs,
    int* __restrict__ rowptr, float* __restrict__ dis, int n, int e)
{
    __shared__ int sdata[256];
    const int base = blockIdx.x * 512;
    const int t = threadIdx.x;
    const int i0 = base + t * 2;
    const int c0 = (i0 < n) ? cnt[i0] : 0;
    const int c1 = (i0 + 1 < n) ? cnt[i0 + 1] : 0;
    sdata[t] = c0 + c1;
    __syncthreads();
#pragma unroll
    for (int off = 1; off < 256; off <<= 1) {
        const int v = (t >= off) ? sdata[t - off] : 0;
        __syncthreads();
        sdata[t] += v;
        __syncthreads();
    }
    const int pre = blockOffs[blockIdx.x] + ((t == 0) ? 0 : sdata[t - 1]);
    if (i0 < n)     { rowptr[i0] = pre;          dis[i0] = rsqrtf(1.0f + (float)c0); }
    if (i0 + 1 < n) { rowptr[i0 + 1] = pre + c0; dis[i0 + 1] = rsqrtf(1.0f + (float)c1); }
    if (blockIdx.x == 0 && t == 0) rowptr[n] = e;
}

__global__ void cursor_init(const int* __restrict__ rowptr, int* cursor, int n) {
    int i = blockIdx.x * blockDim.x + threadIdx.x;
    if (i < n) cursor[i] = rowptr[i];
}

__global__ void scatter_edges(const int* __restrict__ src, const int* __restrict__ dst,
                              int* cursor, int* __restrict__ esrc, int e) {
    int i = blockIdx.x * blockDim.x + threadIdx.x;
    if (i < e) {
        const int pos = atomicAdd(&cursor[dst[i]], 1);
        esrc[pos] = src[i];
    }
}

// ---------------- prep: casts / transposes ----------------
__global__ void cast_x_k(const float* __restrict__ x, ushort* __restrict__ xb, int total8) {
    int i = blockIdx.x * blockDim.x + threadIdx.x;
    if (i >= total8) return;
    const float4 v0 = ((const float4*)x)[(size_t)i * 2];
    const float4 v1 = ((const float4*)x)[(size_t)i * 2 + 1];
    ushort4 a = make_ushort4(f2bf(v0.x), f2bf(v0.y), f2bf(v0.z), f2bf(v0.w));
    ushort4 b = make_ushort4(f2bf(v1.x), f2bf(v1.y), f2bf(v1.z), f2bf(v1.w));
    ((ushort4*)xb)[(size_t)i * 2] = a;
    ((ushort4*)xb)[(size_t)i * 2 + 1] = b;
}

// W [K x Nw] row-major f32 -> Wt [Nrows x Kp] bf16 (zero-padded)
__global__ void transpose_cast(const float* __restrict__ W, ushort* __restrict__ Wt,
                               int K, int Nw, int Kp, int Nrows) {
    int idx = blockIdx.x * blockDim.x + threadIdx.x;
    if (idx >= Nrows * Kp) return;
    const int n = idx / Kp, k = idx - n * Kp;
    Wt[idx] = (k < K && n < Nw) ? f2bf(W[(size_t)k * Nw + n]) : (ushort)0;
}

// ---------------- bf16 MFMA GEMM ----------------
// C[M x Nstore] = A[M x K]_bf16 * Wt[NwRows x K]_bf16^T (+bias)(+relu)
// Block: 256 thr = 4 waves; tile 128 rows x 64 cols; K multiple of 32.
template<bool DO_BIAS, bool DO_RELU, bool OUT_BF16>
__global__ __launch_bounds__(256) void gemm_mfma(
    const ushort* __restrict__ A, int lda, int M,
    const ushort* __restrict__ Wt, int K, int PW, int NwRows,
    const float* __restrict__ bias,
    void* __restrict__ Cout, int ldc, int Nstore)
{
    __shared__ ushort Wt_s[64 * 264];      // pitch PW = K+8 (2-way bank max)
    __shared__ ushort A_s[2][128 * 40];    // pitch 40 (2-way bank max)

    const int tid  = threadIdx.x;
    const int row0 = blockIdx.x * 128;
    const int col0 = blockIdx.y * 64;
    const int lane = tid & 63;
    const int wid  = tid >> 6;
    const int lr = lane & 15;
    const int kg = lane >> 4;

    // ---- load Wt strip (resident for whole K) ----
    const int ku8 = K >> 3;
    for (int idx = tid; idx < 64 * ku8; idx += 256) {
        const int n = idx / ku8;
        const int ku = idx - n * ku8;
        int4 v = make_int4(0, 0, 0, 0);
        const int gn = col0 + n;
        if (gn < NwRows) v = *(const int4*)(Wt + (size_t)gn * K + ku * 8);
        *(int4*)&Wt_s[n * PW + ku * 8] = v;
    }

    // ---- A staging (thread t: row t>>1, 32B chunk) ----
    const int sr = tid >> 1;
    const int so = (tid & 1) * 16;
    const bool rok = (row0 + sr) < M;
    const ushort* Ag = A + (size_t)(row0 + sr) * lda + so;

    int4 s0 = make_int4(0, 0, 0, 0), s1 = s0;
    if (rok) { s0 = *(const int4*)Ag; s1 = *(const int4*)(Ag + 8); }
    *(int4*)&A_s[0][sr * 40 + so] = s0;
    *(int4*)&A_s[0][sr * 40 + so + 8] = s1;

    f32x4 acc[2][4];
#pragma unroll
    for (int m = 0; m < 2; ++m)
#pragma unroll
        for (int n = 0; n < 4; ++n) acc[m][n] = (f32x4){0.f, 0.f, 0.f, 0.f};

    const int nk = K >> 5;
    const int abase = (wid * 32 + lr) * 40 + kg * 8;
    const int bbase = lr * PW + kg * 8;

    for (int kk = 0; kk < nk; ++kk) {
        const bool more = (kk + 1) < nk;
        if (more && rok) {   // prefetch next A tile (global) before compute
            s0 = *(const int4*)(Ag + (kk + 1) * 32);
            s1 = *(const int4*)(Ag + (kk + 1) * 32 + 8);
        }
        __syncthreads();
        const ushort* Ab = A_s[kk & 1];
        bf16x8 a0 = *(const bf16x8*)&Ab[abase];
        bf16x8 a1 = *(const bf16x8*)&Ab[abase + 16 * 40];
        const ushort* Bb = &Wt_s[kk * 32 + bbase];
        bf16x8 b0 = *(const bf16x8*)&Bb[0];
        bf16x8 b1 = *(const bf16x8*)&Bb[16 * PW];
        bf16x8 b2 = *(const bf16x8*)&Bb[32 * PW];
        bf16x8 b3 = *(const bf16x8*)&Bb[48 * PW];
        acc[0][0] = __builtin_amdgcn_mfma_f32_16x16x32_bf16(a0, b0, acc[0][0], 0, 0, 0);
        acc[0][1] = __builtin_amdgcn_mfma_f32_16x16x32_bf16(a0, b1, acc[0][1], 0, 0, 0);
        acc[0][2] = __builtin_amdgcn_mfma_f32_16x16x32_bf16(a0, b2, acc[0][2], 0, 0, 0);
        acc[0][3] = __builtin_amdgcn_mfma_f32_16x16x32_bf16(a0, b3, acc[0][3], 0, 0, 0);
        acc[1][0] = __builtin_amdgcn_mfma_f32_16x16x32_bf16(a1, b0, acc[1][0], 0, 0, 0);
        acc[1][1] = __builtin_amdgcn_mfma_f32_16x16x32_bf16(a1, b1, acc[1][1], 0, 0, 0);
        acc[1][2] = __builtin_amdgcn_mfma_f32_16x16x32_bf16(a1, b2, acc[1][2], 0, 0, 0);
        acc[1][3] = __builtin_amdgcn_mfma_f32_16x16x32_bf16(a1, b3, acc[1][3], 0, 0, 0);
        if (more) {          // write next tile after compute (T14 split)
            *(int4*)&A_s[(kk + 1) & 1][sr * 40 + so] = s0;
            *(int4*)&A_s[(kk + 1) & 1][sr * 40 + so + 8] = s1;
        }
    }

    // ---- epilogue: C/D layout col=lane&15, row=(lane>>4)*4+r ----
#pragma unroll
    for (int m = 0; m < 2; ++m) {
#pragma unroll
        for (int n = 0; n < 4; ++n) {
            const int c = col0 + n * 16 + lr;
            if (c >= Nstore) continue;
            const float bb = DO_BIAS ? bias[c] : 0.f;
            const int r0 = row0 + wid * 32 + m * 16 + kg * 4;
#pragma unroll
            for (int r = 0; r < 4; ++r) {
                const int R = r0 + r;
                if (R >= M) continue;
                float v = acc[m][n][r] + bb;
                if (DO_RELU) v = fmaxf(v, 0.f);
                if (OUT_BF16) ((ushort*)Cout)[(size_t)R * ldc + c] = f2bf(v);
                else          ((float*)Cout)[(size_t)R * ldc + c] = v;
            }
        }
    }
}

// ---------------- glue ----------------
// cat cols 128..159: rw1, action, zeros (K padded to 160)
__global__ void fill_cat_k(ushort* __restrict__ cat, const float* __restrict__ rw1,
                           const float* __restrict__ action, int n) {
    int i = blockIdx.x * blockDim.x + threadIdx.x;
    if (i >= n * 32) return;
    const int node = i >> 5, c = i & 31;
    float v = (c == 0) ? rw1[node] : (c == 1) ? action[node] : 0.f;
    cat[(size_t)node * 160 + 128 + c] = f2bf(v);
}

// hidden = mean + noise*exp(clip(logvar,-5,5)); tmp f32 ld 256 -> hidden bf16 ld 128
__global__ void hidden_k(const float* __restrict__ tmp, const float* __restrict__ noise,
                         ushort* __restrict__ hid, int total) {
    int i = blockIdx.x * blockDim.x + threadIdx.x;
    if (i >= total) return;
    const int row = i >> 7, col = i & 127;
    const float m = tmp[(size_t)row * 256 + col];
    float lv = tmp[(size_t)row * 256 + 128 + col];
    lv = fmaxf(fminf(lv, 5.0f), -5.0f);
    hid[i] = f2bf(m + noise[i] * expf(lv));
}

// ---------------- CSR gather aggregations (bf16 in, f32 accum) ----------------
__global__ __launch_bounds__(256) void agg1_bf(
    const ushort* __restrict__ h, ushort* __restrict__ out,
    const int* __restrict__ rowptr, const int* __restrict__ esrc,
    const float* __restrict__ dis, const float* __restrict__ bias, int n)
{
    const int node = (blockIdx.x * blockDim.x + threadIdx.x) >> 6;
    const int lane = threadIdx.x & 63;
    if (node >= n) return;
    const float dd = dis[node];
    const float d2 = dd * dd;
    float ax, ay, az, aw;
    {
        const ushort4 v = *(const ushort4*)(h + (size_t)node * 256 + lane * 4);
        ax = bf2f(v.x) * d2; ay = bf2f(v.y) * d2; az = bf2f(v.z) * d2; aw = bf2f(v.w) * d2;
    }
    const int b = rowptr[node], e = rowptr[node + 1];
    int j = b;
    for (; j + 1 < e; j += 2) {
        const int s0 = esrc[j], s1 = esrc[j + 1];
        const float n0 = dis[s0] * dd, n1 = dis[s1] * dd;
        const ushort4 v0 = *(const ushort4*)(h + (size_t)s0 * 256 + lane * 4);
        const ushort4 v1 = *(const ushort4*)(h + (size_t)s1 * 256 + lane * 4);
        ax += bf2f(v0.x) * n0 + bf2f(v1.x) * n1;
        ay += bf2f(v0.y) * n0 + bf2f(v1.y) * n1;
        az += bf2f(v0.z) * n0 + bf2f(v1.z) * n1;
        aw += bf2f(v0.w) * n0 + bf2f(v1.w) * n1;
    }
    if (j < e) {
        const int s0 = esrc[j];
        const float n0 = dis[s0] * dd;
        const ushort4 v0 = *(const ushort4*)(h + (size_t)s0 * 256 + lane * 4);
        ax += bf2f(v0.x) * n0; ay += bf2f(v0.y) * n0;
        az += bf2f(v0.z) * n0; aw += bf2f(v0.w) * n0;
    }
    const float4 bb = *(const float4*)(bias + lane * 4);
    ushort4 r = make_ushort4(f2bf(fmaxf(ax + bb.x, 0.f)), f2bf(fmaxf(ay + bb.y, 0.f)),
                             f2bf(fmaxf(az + bb.z, 0.f)), f2bf(fmaxf(aw + bb.w, 0.f)));
    *(ushort4*)(out + (size_t)node * 256 + lane * 4) = r;
}

// agg2: h2 bf16 ld 136 (cols 129..131 zero); fused bias/relu/split -> f32 d_out
__global__ __launch_bounds__(256) void agg2_bf(
    const ushort* __restrict__ h, float* __restrict__ o,
    const int* __restrict__ rowptr, const int* __restrict__ esrc,
    const float* __restrict__ dis, const float* __restrict__ bg2, int n)
{
    const int node = (blockIdx.x * blockDim.x + threadIdx.x) >> 6;
    const int lane = threadIdx.x & 63;
    if (node >= n || lane >= 33) return;
    const float dd = dis[node];
    const float d2 = dd * dd;
    float ax, ay, az, aw;
    {
        const ushort4 v = *(const ushort4*)(h + (size_t)node * 136 + lane * 4);
        ax = bf2f(v.x) * d2; ay = bf2f(v.y) * d2; az = bf2f(v.z) * d2; aw = bf2f(v.w) * d2;
    }
    const int b = rowptr[node], e = rowptr[node + 1];
    int j = b;
    for (; j + 1 < e; j += 2) {
        const int s0 = esrc[j], s1 = esrc[j + 1];
        const float n0 = dis[s0] * dd, n1 = dis[s1] * dd;
        const ushort4 v0 = *(const ushort4*)(h + (size_t)s0 * 136 + lane * 4);
        const ushort4 v1 = *(const ushort4*)(h + (size_t)s1 * 136 + lane * 4);
        ax += bf2f(v0.x) * n0 + bf2f(v1.x) * n1;
        ay += bf2f(v0.y) * n0 + bf2f(v1.y) * n1;
        az += bf2f(v0.z) * n0 + bf2f(v1.z) * n1;
        aw += bf2f(v0.w) * n0 + bf2f(v1.w) * n1;
    }
    if (j < e) {
        const int s0 = esrc[j];
        const float n0 = dis[s0] * dd;
        const ushort4 v0 = *(const ushort4*)(h + (size_t)s0 * 136 + lane * 4);
        ax += bf2f(v0.x) * n0; ay += bf2f(v0.y) * n0;
        az += bf2f(v0.z) * n0; aw += bf2f(v0.w) * n0;
    }
    if (lane < 32) {
        const float4 bb = *(const float4*)(bg2 + lane * 4);
        float4 r;
        r.x = fmaxf(ax + bb.x, 0.f);
        r.y = fmaxf(ay + bb.y, 0.f);
        r.z = fmaxf(az + bb.z, 0.f);
        r.w = fmaxf(aw + bb.w, 0.f);
        *(float4*)(o + (size_t)node * 128 + lane * 4) = r;
    } else {
        o[(size_t)n * 128 + node] = fmaxf(ax + bg2[128], 0.f);
    }
}

extern "C" void kernel_launch(void* const* d_in, const int* in_sizes, int n_in,
                              void* d_out, int out_size, void* d_ws, size_t ws_size,
                              hipStream_t stream)
{
    const float* x      = (const float*)d_in[0];
    const float* rw1    = (const float*)d_in[1];
    const float* action = (const float*)d_in[2];
    const float* noise  = (const float*)d_in[3];
    const int*   eidx   = (const int*)d_in[4];
    const float* W1     = (const float*)d_in[5];
    const float* b1     = (const float*)d_in[6];
    const float* Wg1    = (const float*)d_in[7];
    const float* bg1    = (const float*)d_in[8];
    const float* Whv    = (const float*)d_in[9];
    const float* bhv    = (const float*)d_in[10];
    const float* Wg2    = (const float*)d_in[11];
    const float* bg2    = (const float*)d_in[12];
    const int* src = eidx;
    const int* dst = eidx + NE;

    // Regions (u16 units), 12.8M each:
    // R0: x_bf -> tmp(lo)    R1: cat(8M) -> tmp(hi) -> h2(6.8M)
    // R2: h1 -> hidden       R3: x3a
    ushort* R0 = (ushort*)d_ws;
    ushort* R1 = R0 + 12800000;
    ushort* R2 = R1 + 12800000;
    ushort* R3 = R2 + 12800000;
    float* tmpf = (float*)R0;              // 12.8M f32 spans R0+R1
    float* dis  = (float*)(R3 + 12800000);
    int* cnt    = (int*)(dis + NN);
    int* rowptr = cnt + NN;
    int* esrc   = rowptr + NN + 4;         // padded for alignment
    int* bsums  = esrc + NE;               // 128 block sums
    ushort* Wt1  = (ushort*)(bsums + 128); // [128][256]
    ushort* Wtg1 = Wt1 + 128 * 256;        // [256][160]
    ushort* Whvt = Wtg1 + 256 * 160;       // [256][256]
    ushort* Wg2t = Whvt + 256 * 256;       // [132][128]

    const int T = 256;
    const int gemmRows = (NN + 127) / 128;   // 391
    const int aggBlocks = (NN + 3) / 4;      // one wave per node
    const int scanBlocks = (NN + 511) / 512; // 98

    // ---- prep: casts & weight transposes ----
    cast_x_k<<<(NN * 256 / 8 + T - 1) / T, T, 0, stream>>>(x, R0, NN * 32);
    transpose_cast<<<(128 * 256 + T - 1) / T, T, 0, stream>>>(W1, Wt1, 256, 128, 256, 128);
    transpose_cast<<<(256 * 160 + T - 1) / T, T, 0, stream>>>(Wg1, Wtg1, 130, 256, 160, 256);
    transpose_cast<<<(256 * 256 + T - 1) / T, T, 0, stream>>>(Whv, Whvt, 256, 256, 256, 256);
    transpose_cast<<<(132 * 128 + T - 1) / T, T, 0, stream>>>(Wg2, Wg2t, 128, 129, 128, 132);

    // ---- CSR build (parallel scan) ----
    cnt_zero<<<(NN + T - 1) / T, T, 0, stream>>>(cnt, NN);
    cnt_count<<<(NE + T - 1) / T, T, 0, stream>>>(cnt, dst, NE);
    scan_block_sums<<<scanBlocks, T, 0, stream>>>(cnt, bsums, NN);
    scan_small<<<1, T, 0, stream>>>(bsums, scanBlocks);
    scan_write<<<scanBlocks, T, 0, stream>>>(cnt, bsums, rowptr, dis, NN, NE);
    cursor_init<<<(NN + T - 1) / T, T, 0, stream>>>(rowptr, cnt, NN);
    scatter_edges<<<(NE + T - 1) / T, T, 0, stream>>>(src, dst, cnt, esrc, NE);

    // ---- gemm1: relu(x@W1+b1) -> cat bf16 (ld 160, cols 0..127) ----
    gemm_mfma<true, true, true><<<dim3(gemmRows, 2), T, 0, stream>>>(
        R0, 256, NN, Wt1, 256, 264, 128, b1, R1, 160, 128);
    fill_cat_k<<<(NN * 32 + T - 1) / T, T, 0, stream>>>(R1, rw1, action, NN);

    // ---- gemm2: cat@Wg1 -> h1 bf16 (ld 256) ----
    gemm_mfma<false, false, true><<<dim3(gemmRows, 4), T, 0, stream>>>(
        R1, 160, NN, Wtg1, 160, 168, 256, nullptr, R2, 256, 256);

    // ---- agg1 (+bg1, relu) -> x3a bf16 ----
    agg1_bf<<<aggBlocks, T, 0, stream>>>(R2, R3, rowptr, esrc, dis, bg1, NN);

    // ---- gemm3: relu(x3a@Whv+bhv) -> tmp f32 (ld 256, spans R0+R1) ----
    gemm_mfma<true, true, false><<<dim3(gemmRows, 4), T, 0, stream>>>(
        R3, 256, NN, Whvt, 256, 264, 256, bhv, tmpf, 256, 256);

    // ---- hidden (f32 math) -> bf16 (R2, ld 128) ----
    hidden_k<<<(NN * 128 + T - 1) / T, T, 0, stream>>>(tmpf, noise, R2, NN * 128);

    // ---- gemm4: hidden@Wg2 -> h2 bf16 (ld 136, cols 129..131 zero) ----
    gemm_mfma<false, false, true><<<dim3(gemmRows, 3), T, 0, stream>>>(
        R2, 128, NN, Wg2t, 128, 136, 132, nullptr, R1, 136, 132);

    // ---- agg2 (+bg2, relu, split) -> d_out ----
    agg2_bf<<<aggBlocks, T, 0, stream>>>(R1, (float*)d_out, rowptr, esrc, dis, bg2, NN);
}

// Round 5
// 380.398 us; speedup vs baseline: 12.5809x; 1.0906x over previous
//
#include <hip/hip_runtime.h>

static constexpr int NN = 50000;   // nodes
static constexpr int NE = 800000;  // edges

typedef __attribute__((ext_vector_type(8))) short bf16x8;
typedef __attribute__((ext_vector_type(4))) float f32x4;

__device__ __forceinline__ float bf2f(ushort u) {
    union { unsigned int i; float f; } c; c.i = ((unsigned int)u) << 16; return c.f;
}
__device__ __forceinline__ ushort f2bf(float f) {
    union { float f; unsigned int i; } c; c.f = f;
    unsigned int x = c.i;
    return (ushort)((x + 0x7FFFu + ((x >> 16) & 1u)) >> 16);
}

// ---------------- CSR build ----------------
__global__ void cnt_zero(int* cnt, int n) {
    int i = blockIdx.x * blockDim.x + threadIdx.x;
    if (i < n) cnt[i] = 0;
}

__global__ void cnt_count(int* cnt, const int* __restrict__ dst, int e) {
    int i = blockIdx.x * blockDim.x + threadIdx.x;
    if (i < e) atomicAdd(&cnt[dst[i]], 1);
}

__global__ __launch_bounds__(256) void scan_block_sums(
    const int* __restrict__ cnt, int* __restrict__ blockSums, int n)
{
    __shared__ int sdata[256];
    const int base = blockIdx.x * 512;
    const int t = threadIdx.x;
    const int i0 = base + t * 2;
    int v = 0;
    if (i0 < n) v += cnt[i0];
    if (i0 + 1 < n) v += cnt[i0 + 1];
    sdata[t] = v;
    __syncthreads();
#pragma unroll
    for (int off = 128; off > 0; off >>= 1) {
        if (t < off) sdata[t] += sdata[t + off];
        __syncthreads();
    }
    if (t == 0) blockSums[blockIdx.x] = sdata[0];
}

__global__ __launch_bounds__(256) void scan_small(int* blockSums, int nb) {
    __shared__ int sdata[256];
    const int t = threadIdx.x;
    sdata[t] = (t < nb) ? blockSums[t] : 0;
    __syncthreads();
#pragma unroll
    for (int off = 1; off < 256; off <<= 1) {
        const int v = (t >= off) ? sdata[t - off] : 0;
        __syncthreads();
        sdata[t] += v;
        __syncthreads();
    }
    if (t < nb) blockSums[t] = (t == 0) ? 0 : sdata[t - 1];
}

__global__ __launch_bounds__(256) void scan_write(
    const int* __restrict__ cnt, const int* __restrict__ blockOffs,
    int* __restrict__ rowptr, float* __restrict__ dis, int n, int e)
{
    __shared__ int sdata[256];
    const int base = blockIdx.x * 512;
    const int t = threadIdx.x;
    const int i0 = base + t * 2;
    const int c0 = (i0 < n) ? cnt[i0] : 0;
    const int c1 = (i0 + 1 < n) ? cnt[i0 + 1] : 0;
    sdata[t] = c0 + c1;
    __syncthreads();
#pragma unroll
    for (int off = 1; off < 256; off <<= 1) {
        const int v = (t >= off) ? sdata[t - off] : 0;
        __syncthreads();
        sdata[t] += v;
        __syncthreads();
    }
    const int pre = blockOffs[blockIdx.x] + ((t == 0) ? 0 : sdata[t - 1]);
    if (i0 < n)     { rowptr[i0] = pre;          dis[i0] = rsqrtf(1.0f + (float)c0); }
    if (i0 + 1 < n) { rowptr[i0 + 1] = pre + c0; dis[i0 + 1] = rsqrtf(1.0f + (float)c1); }
    if (blockIdx.x == 0 && t == 0) rowptr[n] = e;
}

__global__ void cursor_init(const int* __restrict__ rowptr, int* cursor, int n) {
    int i = blockIdx.x * blockDim.x + threadIdx.x;
    if (i < n) cursor[i] = rowptr[i];
}

__global__ void scatter_edges(const int* __restrict__ src, const int* __restrict__ dst,
                              int* cursor, int* __restrict__ esrc, int e) {
    int i = blockIdx.x * blockDim.x + threadIdx.x;
    if (i < e) {
        const int pos = atomicAdd(&cursor[dst[i]], 1);
        esrc[pos] = src[i];
    }
}

// ---------------- prep: weight transpose ----------------
// W [K x Nw] row-major f32 -> Wt [Nrows x Kp] bf16 (zero-padded)
__global__ void transpose_cast(const float* __restrict__ W, ushort* __restrict__ Wt,
                               int K, int Nw, int Kp, int Nrows) {
    int idx = blockIdx.x * blockDim.x + threadIdx.x;
    if (idx >= Nrows * Kp) return;
    const int n = idx / Kp, k = idx - n * Kp;
    Wt[idx] = (k < K && n < Nw) ? f2bf(W[(size_t)k * Nw + n]) : (ushort)0;
}

// ---------------- bf16 MFMA GEMM ----------------
// OUT_MODE: 0 = f32 plain, 1 = bf16 plain, 2 = f32 split (cols 0..127 -> o[r*128+c],
//           col 128 -> o[M*128+r]; for the final GCN output).
template<bool A_F32, bool DO_BIAS, bool DO_RELU, int OUT_MODE>
__global__ __launch_bounds__(256) void gemm_mfma(
    const void* __restrict__ Aptr, int lda, int M,
    const ushort* __restrict__ Wt, int K, int PW, int NwRows,
    const float* __restrict__ bias,
    void* __restrict__ Cout, int ldc, int Nstore)
{
    __shared__ ushort Wt_s[64 * 264];      // pitch PW (<= 264)
    __shared__ ushort A_s[2][128 * 40];    // pitch 40

    const int tid  = threadIdx.x;
    const int row0 = blockIdx.x * 128;
    const int col0 = blockIdx.y * 64;
    const int lane = tid & 63;
    const int wid  = tid >> 6;
    const int lr = lane & 15;
    const int kg = lane >> 4;

    // ---- load Wt strip (resident for whole K) ----
    const int ku8 = K >> 3;
    for (int idx = tid; idx < 64 * ku8; idx += 256) {
        const int n = idx / ku8;
        const int ku = idx - n * ku8;
        int4 v = make_int4(0, 0, 0, 0);
        const int gn = col0 + n;
        if (gn < NwRows) v = *(const int4*)(Wt + (size_t)gn * K + ku * 8);
        *(int4*)&Wt_s[n * PW + ku * 8] = v;
    }

    // ---- A staging (thread t: row t>>1, 16-elem chunk) ----
    const int sr = tid >> 1;
    const int so = (tid & 1) * 16;
    const bool rok = (row0 + sr) < M;

    const ushort* Agu = (const ushort*)Aptr + (size_t)(row0 + sr) * lda + so;
    const float*  Agf = (const float*)Aptr + (size_t)(row0 + sr) * lda + so;

    int4 s0 = make_int4(0, 0, 0, 0), s1 = s0;
    auto load_chunk = [&](int koff) {
        if (!A_F32) {
            const ushort* p = Agu + koff;
            s0 = *(const int4*)p;
            s1 = *(const int4*)(p + 8);
        } else {
            const float* p = Agf + koff;
            const float4 f0 = *(const float4*)(p + 0);
            const float4 f1 = *(const float4*)(p + 4);
            const float4 f2 = *(const float4*)(p + 8);
            const float4 f3 = *(const float4*)(p + 12);
            s0.x = (int)f2bf(f0.x) | ((int)f2bf(f0.y) << 16);
            s0.y = (int)f2bf(f0.z) | ((int)f2bf(f0.w) << 16);
            s0.z = (int)f2bf(f1.x) | ((int)f2bf(f1.y) << 16);
            s0.w = (int)f2bf(f1.z) | ((int)f2bf(f1.w) << 16);
            s1.x = (int)f2bf(f2.x) | ((int)f2bf(f2.y) << 16);
            s1.y = (int)f2bf(f2.z) | ((int)f2bf(f2.w) << 16);
            s1.z = (int)f2bf(f3.x) | ((int)f2bf(f3.y) << 16);
            s1.w = (int)f2bf(f3.z) | ((int)f2bf(f3.w) << 16);
        }
    };

    if (rok) load_chunk(0);
    *(int4*)&A_s[0][sr * 40 + so] = s0;
    *(int4*)&A_s[0][sr * 40 + so + 8] = s1;

    f32x4 acc[2][4];
#pragma unroll
    for (int m = 0; m < 2; ++m)
#pragma unroll
        for (int n = 0; n < 4; ++n) acc[m][n] = (f32x4){0.f, 0.f, 0.f, 0.f};

    const int nk = K >> 5;
    const int abase = (wid * 32 + lr) * 40 + kg * 8;
    const int bbase = lr * PW + kg * 8;

    for (int kk = 0; kk < nk; ++kk) {
        const bool more = (kk + 1) < nk;
        if (more && rok) load_chunk((kk + 1) * 32);
        __syncthreads();
        const ushort* Ab = A_s[kk & 1];
        bf16x8 a0 = *(const bf16x8*)&Ab[abase];
        bf16x8 a1 = *(const bf16x8*)&Ab[abase + 16 * 40];
        const ushort* Bb = &Wt_s[kk * 32 + bbase];
        bf16x8 b0 = *(const bf16x8*)&Bb[0];
        bf16x8 b1 = *(const bf16x8*)&Bb[16 * PW];
        bf16x8 b2 = *(const bf16x8*)&Bb[32 * PW];
        bf16x8 b3 = *(const bf16x8*)&Bb[48 * PW];
        acc[0][0] = __builtin_amdgcn_mfma_f32_16x16x32_bf16(a0, b0, acc[0][0], 0, 0, 0);
        acc[0][1] = __builtin_amdgcn_mfma_f32_16x16x32_bf16(a0, b1, acc[0][1], 0, 0, 0);
        acc[0][2] = __builtin_amdgcn_mfma_f32_16x16x32_bf16(a0, b2, acc[0][2], 0, 0, 0);
        acc[0][3] = __builtin_amdgcn_mfma_f32_16x16x32_bf16(a0, b3, acc[0][3], 0, 0, 0);
        acc[1][0] = __builtin_amdgcn_mfma_f32_16x16x32_bf16(a1, b0, acc[1][0], 0, 0, 0);
        acc[1][1] = __builtin_amdgcn_mfma_f32_16x16x32_bf16(a1, b1, acc[1][1], 0, 0, 0);
        acc[1][2] = __builtin_amdgcn_mfma_f32_16x16x32_bf16(a1, b2, acc[1][2], 0, 0, 0);
        acc[1][3] = __builtin_amdgcn_mfma_f32_16x16x32_bf16(a1, b3, acc[1][3], 0, 0, 0);
        if (more) {
            *(int4*)&A_s[(kk + 1) & 1][sr * 40 + so] = s0;
            *(int4*)&A_s[(kk + 1) & 1][sr * 40 + so + 8] = s1;
        }
    }

    // ---- epilogue: C/D layout col=lane&15, row=(lane>>4)*4+r ----
#pragma unroll
    for (int m = 0; m < 2; ++m) {
#pragma unroll
        for (int n = 0; n < 4; ++n) {
            const int c = col0 + n * 16 + lr;
            if (c >= Nstore) continue;
            const float bb = DO_BIAS ? bias[c] : 0.f;
            const int r0 = row0 + wid * 32 + m * 16 + kg * 4;
#pragma unroll
            for (int r = 0; r < 4; ++r) {
                const int R = r0 + r;
                if (R >= M) continue;
                float v = acc[m][n][r] + bb;
                if (DO_RELU) v = fmaxf(v, 0.f);
                if (OUT_MODE == 1) {
                    ((ushort*)Cout)[(size_t)R * ldc + c] = f2bf(v);
                } else if (OUT_MODE == 0) {
                    ((float*)Cout)[(size_t)R * ldc + c] = v;
                } else {  // split: GCN2 output
                    float* o = (float*)Cout;
                    if (c < 128) o[(size_t)R * 128 + c] = v;
                    else         o[(size_t)M * 128 + R] = v;
                }
            }
        }
    }
}

// ---------------- glue ----------------
// cat cols 128..159: rw1, action, zeros
__global__ void fill_cat_k(ushort* __restrict__ cat, const float* __restrict__ rw1,
                           const float* __restrict__ action, int n) {
    int i = blockIdx.x * blockDim.x + threadIdx.x;
    if (i >= n * 32) return;
    const int node = i >> 5, c = i & 31;
    float v = (c == 0) ? rw1[node] : (c == 1) ? action[node] : 0.f;
    cat[(size_t)node * 160 + 128 + c] = f2bf(v);
}

// hidden = mean + noise*exp(clip(logvar,-5,5)); tmp f32 ld 256 -> hidden bf16 ld 128
__global__ void hidden_k(const float* __restrict__ tmp, const float* __restrict__ noise,
                         ushort* __restrict__ hid, int total) {
    int i = blockIdx.x * blockDim.x + threadIdx.x;
    if (i >= total) return;
    const int row = i >> 7, col = i & 127;
    const float m = tmp[(size_t)row * 256 + col];
    float lv = tmp[(size_t)row * 256 + 128 + col];
    lv = fmaxf(fminf(lv, 5.0f), -5.0f);
    hid[i] = f2bf(m + noise[i] * expf(lv));
}

// ---------------- CSR gather aggregations on NARROW tensors ----------------
// agg_cat: in/out ld 160 bf16; gather cols 0..131 (33 lanes), zero cols 132..159.
__global__ __launch_bounds__(256) void agg_cat(
    const ushort* __restrict__ h, ushort* __restrict__ out,
    const int* __restrict__ rowptr, const int* __restrict__ esrc,
    const float* __restrict__ dis, int n)
{
    const int node = (blockIdx.x * blockDim.x + threadIdx.x) >> 6;
    const int lane = threadIdx.x & 63;
    if (node >= n || lane >= 40) return;
    if (lane >= 33) {   // zero the K-pad cols 132..159
        *(ushort4*)(out + (size_t)node * 160 + lane * 4) = make_ushort4(0, 0, 0, 0);
        return;
    }
    const float dd = dis[node];
    const float d2 = dd * dd;
    float ax, ay, az, aw;
    {
        const ushort4 v = *(const ushort4*)(h + (size_t)node * 160 + lane * 4);
        ax = bf2f(v.x) * d2; ay = bf2f(v.y) * d2; az = bf2f(v.z) * d2; aw = bf2f(v.w) * d2;
    }
    const int b = rowptr[node], e = rowptr[node + 1];
    int j = b;
    for (; j + 3 < e; j += 4) {
        const int s0 = esrc[j], s1 = esrc[j + 1], s2 = esrc[j + 2], s3 = esrc[j + 3];
        const float n0 = dis[s0] * dd, n1 = dis[s1] * dd, n2 = dis[s2] * dd, n3 = dis[s3] * dd;
        const ushort4 v0 = *(const ushort4*)(h + (size_t)s0 * 160 + lane * 4);
        const ushort4 v1 = *(const ushort4*)(h + (size_t)s1 * 160 + lane * 4);
        const ushort4 v2 = *(const ushort4*)(h + (size_t)s2 * 160 + lane * 4);
        const ushort4 v3 = *(const ushort4*)(h + (size_t)s3 * 160 + lane * 4);
        ax += bf2f(v0.x) * n0 + bf2f(v1.x) * n1 + bf2f(v2.x) * n2 + bf2f(v3.x) * n3;
        ay += bf2f(v0.y) * n0 + bf2f(v1.y) * n1 + bf2f(v2.y) * n2 + bf2f(v3.y) * n3;
        az += bf2f(v0.z) * n0 + bf2f(v1.z) * n1 + bf2f(v2.z) * n2 + bf2f(v3.z) * n3;
        aw += bf2f(v0.w) * n0 + bf2f(v1.w) * n1 + bf2f(v2.w) * n2 + bf2f(v3.w) * n3;
    }
    for (; j < e; ++j) {
        const int s0 = esrc[j];
        const float n0 = dis[s0] * dd;
        const ushort4 v0 = *(const ushort4*)(h + (size_t)s0 * 160 + lane * 4);
        ax += bf2f(v0.x) * n0; ay += bf2f(v0.y) * n0;
        az += bf2f(v0.z) * n0; aw += bf2f(v0.w) * n0;
    }
    ushort4 r = make_ushort4(f2bf(ax), f2bf(ay), f2bf(az), f2bf(aw));
    *(ushort4*)(out + (size_t)node * 160 + lane * 4) = r;
}

// agg_hid: in/out ld 128 bf16 (32 lanes)
__global__ __launch_bounds__(256) void agg_hid(
    const ushort* __restrict__ h, ushort* __restrict__ out,
    const int* __restrict__ rowptr, const int* __restrict__ esrc,
    const float* __restrict__ dis, int n)
{
    const int node = (blockIdx.x * blockDim.x + threadIdx.x) >> 6;
    const int lane = threadIdx.x & 63;
    if (node >= n || lane >= 32) return;
    const float dd = dis[node];
    const float d2 = dd * dd;
    float ax, ay, az, aw;
    {
        const ushort4 v = *(const ushort4*)(h + (size_t)node * 128 + lane * 4);
        ax = bf2f(v.x) * d2; ay = bf2f(v.y) * d2; az = bf2f(v.z) * d2; aw = bf2f(v.w) * d2;
    }
    const int b = rowptr[node], e = rowptr[node + 1];
    int j = b;
    for (; j + 3 < e; j += 4) {
        const int s0 = esrc[j], s1 = esrc[j + 1], s2 = esrc[j + 2], s3 = esrc[j + 3];
        const float n0 = dis[s0] * dd, n1 = dis[s1] * dd, n2 = dis[s2] * dd, n3 = dis[s3] * dd;
        const ushort4 v0 = *(const ushort4*)(h + (size_t)s0 * 128 + lane * 4);
        const ushort4 v1 = *(const ushort4*)(h + (size_t)s1 * 128 + lane * 4);
        const ushort4 v2 = *(const ushort4*)(h + (size_t)s2 * 128 + lane * 4);
        const ushort4 v3 = *(const ushort4*)(h + (size_t)s3 * 128 + lane * 4);
        ax += bf2f(v0.x) * n0 + bf2f(v1.x) * n1 + bf2f(v2.x) * n2 + bf2f(v3.x) * n3;
        ay += bf2f(v0.y) * n0 + bf2f(v1.y) * n1 + bf2f(v2.y) * n2 + bf2f(v3.y) * n3;
        az += bf2f(v0.z) * n0 + bf2f(v1.z) * n1 + bf2f(v2.z) * n2 + bf2f(v3.z) * n3;
        aw += bf2f(v0.w) * n0 + bf2f(v1.w) * n1 + bf2f(v2.w) * n2 + bf2f(v3.w) * n3;
    }
    for (; j < e; ++j) {
        const int s0 = esrc[j];
        const float n0 = dis[s0] * dd;
        const ushort4 v0 = *(const ushort4*)(h + (size_t)s0 * 128 + lane * 4);
        ax += bf2f(v0.x) * n0; ay += bf2f(v0.y) * n0;
        az += bf2f(v0.z) * n0; aw += bf2f(v0.w) * n0;
    }
    ushort4 r = make_ushort4(f2bf(ax), f2bf(ay), f2bf(az), f2bf(aw));
    *(ushort4*)(out + (size_t)node * 128 + lane * 4) = r;
}

extern "C" void kernel_launch(void* const* d_in, const int* in_sizes, int n_in,
                              void* d_out, int out_size, void* d_ws, size_t ws_size,
                              hipStream_t stream)
{
    const float* x      = (const float*)d_in[0];
    const float* rw1    = (const float*)d_in[1];
    const float* action = (const float*)d_in[2];
    const float* noise  = (const float*)d_in[3];
    const int*   eidx   = (const int*)d_in[4];
    const float* W1     = (const float*)d_in[5];
    const float* b1     = (const float*)d_in[6];
    const float* Wg1    = (const float*)d_in[7];
    const float* bg1    = (const float*)d_in[8];
    const float* Whv    = (const float*)d_in[9];
    const float* bhv    = (const float*)d_in[10];
    const float* Wg2    = (const float*)d_in[11];
    const float* bg2    = (const float*)d_in[12];
    const int* src = eidx;
    const int* dst = eidx + NE;

    // Regions (u16 units), 12.8M each:
    // R0+R1: tmp f32 (after cat dies)   R1: cat (8M)
    // R2: x3a -> hidden                 R3: aggcat (8M) -> agghid (6.4M)
    ushort* R0 = (ushort*)d_ws;
    ushort* R1 = R0 + 12800000;
    ushort* R2 = R1 + 12800000;
    ushort* R3 = R2 + 12800000;
    float* tmpf = (float*)R0;              // 12.8M f32 spans R0+R1
    float* dis  = (float*)(R3 + 12800000);
    int* cnt    = (int*)(dis + NN);
    int* rowptr = cnt + NN;
    int* esrc   = rowptr + NN + 4;
    int* bsums  = esrc + NE;
    ushort* Wt1  = (ushort*)(bsums + 128); // [128][256]
    ushort* Wtg1 = Wt1 + 128 * 256;        // [256][160]
    ushort* Whvt = Wtg1 + 256 * 160;       // [256][256]
    ushort* Wg2t = Whvt + 256 * 256;       // [132][128]

    const int T = 256;
    const int gemmRows = (NN + 127) / 128;   // 391
    const int aggBlocks = (NN + 3) / 4;
    const int scanBlocks = (NN + 511) / 512; // 98

    // ---- prep: weight transposes ----
    transpose_cast<<<(128 * 256 + T - 1) / T, T, 0, stream>>>(W1, Wt1, 256, 128, 256, 128);
    transpose_cast<<<(256 * 160 + T - 1) / T, T, 0, stream>>>(Wg1, Wtg1, 130, 256, 160, 256);
    transpose_cast<<<(256 * 256 + T - 1) / T, T, 0, stream>>>(Whv, Whvt, 256, 256, 256, 256);
    transpose_cast<<<(132 * 128 + T - 1) / T, T, 0, stream>>>(Wg2, Wg2t, 128, 129, 128, 132);

    // ---- CSR build ----
    cnt_zero<<<(NN + T - 1) / T, T, 0, stream>>>(cnt, NN);
    cnt_count<<<(NE + T - 1) / T, T, 0, stream>>>(cnt, dst, NE);
    scan_block_sums<<<scanBlocks, T, 0, stream>>>(cnt, bsums, NN);
    scan_small<<<1, T, 0, stream>>>(bsums, scanBlocks);
    scan_write<<<scanBlocks, T, 0, stream>>>(cnt, bsums, rowptr, dis, NN, NE);
    cursor_init<<<(NN + T - 1) / T, T, 0, stream>>>(rowptr, cnt, NN);
    scatter_edges<<<(NE + T - 1) / T, T, 0, stream>>>(src, dst, cnt, esrc, NE);

    // ---- gemm1: relu(x@W1+b1) -> cat bf16 (R1, ld 160, cols 0..127); A = f32 x ----
    gemm_mfma<true, true, true, 1><<<dim3(gemmRows, 2), T, 0, stream>>>(
        x, 256, NN, Wt1, 256, 264, 128, b1, R1, 160, 128);
    fill_cat_k<<<(NN * 32 + T - 1) / T, T, 0, stream>>>(R1, rw1, action, NN);

    // ---- agg1 on cat (132 feats) -> aggcat (R3, ld 160) ----
    agg_cat<<<aggBlocks, T, 0, stream>>>(R1, R3, rowptr, esrc, dis, NN);

    // ---- gemm2: relu(aggcat@Wg1 + bg1) -> x3a bf16 (R2, ld 256) ----
    gemm_mfma<false, true, true, 1><<<dim3(gemmRows, 4), T, 0, stream>>>(
        R3, 160, NN, Wtg1, 160, 168, 256, bg1, R2, 256, 256);

    // ---- gemm3: relu(x3a@Whv+bhv) -> tmp f32 (ld 256, spans R0+R1) ----
    gemm_mfma<false, true, true, 0><<<dim3(gemmRows, 4), T, 0, stream>>>(
        R2, 256, NN, Whvt, 256, 264, 256, bhv, tmpf, 256, 256);

    // ---- hidden (f32 math) -> bf16 (R2, ld 128) ----
    hidden_k<<<(NN * 128 + T - 1) / T, T, 0, stream>>>(tmpf, noise, R2, NN * 128);

    // ---- agg2 on hidden (128 feats) -> agghid (R3, ld 128) ----
    agg_hid<<<aggBlocks, T, 0, stream>>>(R2, R3, rowptr, esrc, dis, NN);

    // ---- gemm4: relu(agghid@Wg2 + bg2), fused split -> d_out ----
    gemm_mfma<false, true, true, 2><<<dim3(gemmRows, 3), T, 0, stream>>>(
        R3, 128, NN, Wg2t, 128, 136, 129, bg2, d_out, 0, 129);
}

// Round 6
// 339.134 us; speedup vs baseline: 14.1116x; 1.1217x over previous
//
#include <hip/hip_runtime.h>

static constexpr int NN = 50000;   // nodes
static constexpr int NE = 800000;  // edges

typedef __attribute__((ext_vector_type(8))) short bf16x8;
typedef __attribute__((ext_vector_type(4))) float f32x4;

__device__ __forceinline__ float bf2f(ushort u) {
    union { unsigned int i; float f; } c; c.i = ((unsigned int)u) << 16; return c.f;
}
__device__ __forceinline__ ushort f2bf(float f) {
    union { float f; unsigned int i; } c; c.f = f;
    unsigned int x = c.i;
    return (ushort)((x + 0x7FFFu + ((x >> 16) & 1u)) >> 16);
}
__device__ __forceinline__ int packbf(float a, float b) {
    return (int)f2bf(a) | ((int)f2bf(b) << 16);
}

// ---------------- CSR build ----------------
__global__ void cnt_count(int* cnt, const int* __restrict__ dst, int e) {
    int i = blockIdx.x * blockDim.x + threadIdx.x;
    if (i < e) atomicAdd(&cnt[dst[i]], 1);
}

__global__ __launch_bounds__(256) void scan_block_sums(
    const int* __restrict__ cnt, int* __restrict__ blockSums, int n)
{
    __shared__ int sdata[256];
    const int base = blockIdx.x * 512;
    const int t = threadIdx.x;
    const int i0 = base + t * 2;
    int v = 0;
    if (i0 < n) v += cnt[i0];
    if (i0 + 1 < n) v += cnt[i0 + 1];
    sdata[t] = v;
    __syncthreads();
#pragma unroll
    for (int off = 128; off > 0; off >>= 1) {
        if (t < off) sdata[t] += sdata[t + off];
        __syncthreads();
    }
    if (t == 0) blockSums[blockIdx.x] = sdata[0];
}

__global__ __launch_bounds__(256) void scan_small(int* blockSums, int nb) {
    __shared__ int sdata[256];
    const int t = threadIdx.x;
    sdata[t] = (t < nb) ? blockSums[t] : 0;
    __syncthreads();
#pragma unroll
    for (int off = 1; off < 256; off <<= 1) {
        const int v = (t >= off) ? sdata[t - off] : 0;
        __syncthreads();
        sdata[t] += v;
        __syncthreads();
    }
    if (t < nb) blockSums[t] = (t == 0) ? 0 : sdata[t - 1];
}

// writes rowptr, cursor (=cnt, in place), dis
__global__ __launch_bounds__(256) void scan_write(
    int* __restrict__ cnt, const int* __restrict__ blockOffs,
    int* __restrict__ rowptr, float* __restrict__ dis, int n, int e)
{
    __shared__ int sdata[256];
    const int base = blockIdx.x * 512;
    const int t = threadIdx.x;
    const int i0 = base + t * 2;
    const int c0 = (i0 < n) ? cnt[i0] : 0;
    const int c1 = (i0 + 1 < n) ? cnt[i0 + 1] : 0;
    sdata[t] = c0 + c1;
    __syncthreads();
#pragma unroll
    for (int off = 1; off < 256; off <<= 1) {
        const int v = (t >= off) ? sdata[t - off] : 0;
        __syncthreads();
        sdata[t] += v;
        __syncthreads();
    }
    const int pre = blockOffs[blockIdx.x] + ((t == 0) ? 0 : sdata[t - 1]);
    if (i0 < n) {
        rowptr[i0] = pre; cnt[i0] = pre;
        dis[i0] = rsqrtf(1.0f + (float)c0);
    }
    if (i0 + 1 < n) {
        rowptr[i0 + 1] = pre + c0; cnt[i0 + 1] = pre + c0;
        dis[i0 + 1] = rsqrtf(1.0f + (float)c1);
    }
    if (blockIdx.x == 0 && t == 0) rowptr[n] = e;
}

__global__ void scatter_edges(const int* __restrict__ src, const int* __restrict__ dst,
                              int* cursor, int* __restrict__ esrc, int e) {
    int i = blockIdx.x * blockDim.x + threadIdx.x;
    if (i < e) {
        const int pos = atomicAdd(&cursor[dst[i]], 1);
        esrc[pos] = src[i];
    }
}

// ---------------- prep: all 4 weight transposes in one kernel ----------------
__global__ void transpose_all(const float* __restrict__ W1, const float* __restrict__ Wg1,
                              const float* __restrict__ Whv, const float* __restrict__ Wg2,
                              ushort* __restrict__ Wt1, ushort* __restrict__ Wtg1,
                              ushort* __restrict__ Whvt, ushort* __restrict__ Wg2t)
{
    int idx = blockIdx.x * blockDim.x + threadIdx.x;
    if (idx < 128 * 256) {                 // Wt1 [128][256] <- W1 [256][128]
        const int n = idx >> 8, k = idx & 255;
        Wt1[idx] = f2bf(W1[k * 128 + n]);
        return;
    }
    idx -= 128 * 256;
    if (idx < 256 * 160) {                 // Wtg1 [256][160] <- Wg1 [130][256]
        const int n = idx / 160, k = idx - n * 160;
        Wtg1[idx] = (k < 130) ? f2bf(Wg1[k * 256 + n]) : (ushort)0;
        return;
    }
    idx -= 256 * 160;
    if (idx < 256 * 256) {                 // Whvt [256][256] <- Whv [256][256]
        const int n = idx >> 8, k = idx & 255;
        Whvt[idx] = f2bf(Whv[k * 256 + n]);
        return;
    }
    idx -= 256 * 256;
    if (idx < 132 * 128) {                 // Wg2t [132][128] <- Wg2 [128][129]
        const int n = idx >> 7, k = idx & 127;
        Wg2t[idx] = (n < 129) ? f2bf(Wg2[k * 129 + n]) : (ushort)0;
    }
}

// ---------------- bf16 MFMA GEMM ----------------
// AMODE: 0 = A bf16 (lda), 1 = A f32 cast-on-stage, 2 = A bf16 ld128 main +
//        chunk k>=128 synthesized from aggra (cols 128,129) + zeros.
// OUT_MODE: 0 = f32 plain, 1 = bf16 plain, 2 = f32 split (cols 0..127 ->
//           o[r*128+c], col 128 -> o[M*128+r]).
template<int AMODE, bool DO_BIAS, bool DO_RELU, int OUT_MODE>
__global__ __launch_bounds__(256) void gemm_mfma(
    const void* __restrict__ Aptr, int lda, int M,
    const float2* __restrict__ aggra,
    const ushort* __restrict__ Wt, int K, int PW, int NwRows,
    const float* __restrict__ bias,
    void* __restrict__ Cout, int ldc, int Nstore)
{
    __shared__ ushort Wt_s[64 * 264];      // pitch PW (<= 264)
    __shared__ ushort A_s[2][128 * 40];    // pitch 40

    const int tid  = threadIdx.x;
    const int row0 = blockIdx.x * 128;
    const int col0 = blockIdx.y * 64;
    const int lane = tid & 63;
    const int wid  = tid >> 6;
    const int lr = lane & 15;
    const int kg = lane >> 4;

    // ---- load Wt strip (resident for whole K) ----
    const int ku8 = K >> 3;
    for (int idx = tid; idx < 64 * ku8; idx += 256) {
        const int n = idx / ku8;
        const int ku = idx - n * ku8;
        int4 v = make_int4(0, 0, 0, 0);
        const int gn = col0 + n;
        if (gn < NwRows) v = *(const int4*)(Wt + (size_t)gn * K + ku * 8);
        *(int4*)&Wt_s[n * PW + ku * 8] = v;
    }

    // ---- A staging (thread t: row t>>1, 16-elem chunk) ----
    const int sr = tid >> 1;
    const int so = (tid & 1) * 16;
    const bool rok = (row0 + sr) < M;

    const ushort* Agu = (const ushort*)Aptr + (size_t)(row0 + sr) * lda + so;
    const float*  Agf = (const float*)Aptr + (size_t)(row0 + sr) * lda + so;

    int4 s0 = make_int4(0, 0, 0, 0), s1 = s0;
    auto load_chunk = [&](int koff) {
        if (AMODE == 2 && koff >= 128) {
            s0 = make_int4(0, 0, 0, 0); s1 = s0;
            if (so == 0) {
                const float2 ra = aggra[row0 + sr];
                s0.x = packbf(ra.x, ra.y);
            }
        } else if (AMODE == 1) {
            const float* p = Agf + koff;
            const float4 f0 = *(const float4*)(p + 0);
            const float4 f1 = *(const float4*)(p + 4);
            const float4 f2 = *(const float4*)(p + 8);
            const float4 f3 = *(const float4*)(p + 12);
            s0.x = packbf(f0.x, f0.y); s0.y = packbf(f0.z, f0.w);
            s0.z = packbf(f1.x, f1.y); s0.w = packbf(f1.z, f1.w);
            s1.x = packbf(f2.x, f2.y); s1.y = packbf(f2.z, f2.w);
            s1.z = packbf(f3.x, f3.y); s1.w = packbf(f3.z, f3.w);
        } else {
            const ushort* p = Agu + koff;
            s0 = *(const int4*)p;
            s1 = *(const int4*)(p + 8);
        }
    };

    if (rok) load_chunk(0);
    *(int4*)&A_s[0][sr * 40 + so] = s0;
    *(int4*)&A_s[0][sr * 40 + so + 8] = s1;

    f32x4 acc[2][4];
#pragma unroll
    for (int m = 0; m < 2; ++m)
#pragma unroll
        for (int n = 0; n < 4; ++n) acc[m][n] = (f32x4){0.f, 0.f, 0.f, 0.f};

    const int nk = K >> 5;
    const int abase = (wid * 32 + lr) * 40 + kg * 8;
    const int bbase = lr * PW + kg * 8;

    for (int kk = 0; kk < nk; ++kk) {
        const bool more = (kk + 1) < nk;
        if (more && rok) load_chunk((kk + 1) * 32);
        __syncthreads();
        const ushort* Ab = A_s[kk & 1];
        bf16x8 a0 = *(const bf16x8*)&Ab[abase];
        bf16x8 a1 = *(const bf16x8*)&Ab[abase + 16 * 40];
        const ushort* Bb = &Wt_s[kk * 32 + bbase];
        bf16x8 b0 = *(const bf16x8*)&Bb[0];
        bf16x8 b1 = *(const bf16x8*)&Bb[16 * PW];
        bf16x8 b2 = *(const bf16x8*)&Bb[32 * PW];
        bf16x8 b3 = *(const bf16x8*)&Bb[48 * PW];
        acc[0][0] = __builtin_amdgcn_mfma_f32_16x16x32_bf16(a0, b0, acc[0][0], 0, 0, 0);
        acc[0][1] = __builtin_amdgcn_mfma_f32_16x16x32_bf16(a0, b1, acc[0][1], 0, 0, 0);
        acc[0][2] = __builtin_amdgcn_mfma_f32_16x16x32_bf16(a0, b2, acc[0][2], 0, 0, 0);
        acc[0][3] = __builtin_amdgcn_mfma_f32_16x16x32_bf16(a0, b3, acc[0][3], 0, 0, 0);
        acc[1][0] = __builtin_amdgcn_mfma_f32_16x16x32_bf16(a1, b0, acc[1][0], 0, 0, 0);
        acc[1][1] = __builtin_amdgcn_mfma_f32_16x16x32_bf16(a1, b1, acc[1][1], 0, 0, 0);
        acc[1][2] = __builtin_amdgcn_mfma_f32_16x16x32_bf16(a1, b2, acc[1][2], 0, 0, 0);
        acc[1][3] = __builtin_amdgcn_mfma_f32_16x16x32_bf16(a1, b3, acc[1][3], 0, 0, 0);
        if (more) {
            *(int4*)&A_s[(kk + 1) & 1][sr * 40 + so] = s0;
            *(int4*)&A_s[(kk + 1) & 1][sr * 40 + so + 8] = s1;
        }
    }

    // ---- epilogue: C/D layout col=lane&15, row=(lane>>4)*4+r ----
#pragma unroll
    for (int m = 0; m < 2; ++m) {
#pragma unroll
        for (int n = 0; n < 4; ++n) {
            const int c = col0 + n * 16 + lr;
            if (c >= Nstore) continue;
            const float bb = DO_BIAS ? bias[c] : 0.f;
            const int r0 = row0 + wid * 32 + m * 16 + kg * 4;
#pragma unroll
            for (int r = 0; r < 4; ++r) {
                const int R = r0 + r;
                if (R >= M) continue;
                float v = acc[m][n][r] + bb;
                if (DO_RELU) v = fmaxf(v, 0.f);
                if (OUT_MODE == 1) {
                    ((ushort*)Cout)[(size_t)R * ldc + c] = f2bf(v);
                } else if (OUT_MODE == 0) {
                    ((float*)Cout)[(size_t)R * ldc + c] = v;
                } else {  // split: GCN2 output
                    float* o = (float*)Cout;
                    if (c < 128) o[(size_t)R * 128 + c] = v;
                    else         o[(size_t)M * 128 + R] = v;
                }
            }
        }
    }
}

// ---------------- glue ----------------
// hidden = mean + noise*exp(clip(logvar,-5,5)); tmp bf16 ld 256 -> hidden bf16 ld 128
__global__ void hidden_k(const ushort* __restrict__ tmp, const float* __restrict__ noise,
                         ushort* __restrict__ hid, int n32) {
    int i = blockIdx.x * blockDim.x + threadIdx.x;
    if (i >= n32) return;
    const int row = i >> 5, c4 = (i & 31) * 4;
    const ushort4 mu = *(const ushort4*)(tmp + (size_t)row * 256 + c4);
    const ushort4 lg = *(const ushort4*)(tmp + (size_t)row * 256 + 128 + c4);
    const float4 nz = *(const float4*)(noise + (size_t)row * 128 + c4);
    ushort4 r;
    r.x = f2bf(bf2f(mu.x) + nz.x * expf(fminf(fmaxf(bf2f(lg.x), -5.f), 5.f)));
    r.y = f2bf(bf2f(mu.y) + nz.y * expf(fminf(fmaxf(bf2f(lg.y), -5.f), 5.f)));
    r.z = f2bf(bf2f(mu.z) + nz.z * expf(fminf(fmaxf(bf2f(lg.z), -5.f), 5.f)));
    r.w = f2bf(bf2f(mu.w) + nz.w * expf(fminf(fmaxf(bf2f(lg.w), -5.f), 5.f)));
    *(ushort4*)(hid + (size_t)row * 128 + c4) = r;
}

// ---------------- CSR gather aggregation, 128-col bf16 rows ----------------
// One wave per node; 16 lanes per edge row (int4 = 16B/lane), 4 edges in flight;
// butterfly reduce across the 4 edge groups at the end.
__global__ __launch_bounds__(256) void agg128(
    const ushort* __restrict__ h, ushort* __restrict__ out,
    const int* __restrict__ rowptr, const int* __restrict__ esrc,
    const float* __restrict__ dis, int n)
{
    const int node = (blockIdx.x * blockDim.x + threadIdx.x) >> 6;
    if (node >= n) return;
    const int lane = threadIdx.x & 63;
    const int g = lane >> 4;        // edge group 0..3
    const int sub = lane & 15;      // 8-col chunk
    const float dd = dis[node];

    float acc[8] = {0.f, 0.f, 0.f, 0.f, 0.f, 0.f, 0.f, 0.f};
    if (g == 0) {   // self loop, counted once
        const int4 v = *(const int4*)(h + (size_t)node * 128 + sub * 8);
        const float d2 = dd * dd;
        acc[0] = bf2f((ushort)(v.x & 0xffff)) * d2;
        acc[1] = bf2f((ushort)((unsigned)v.x >> 16)) * d2;
        acc[2] = bf2f((ushort)(v.y & 0xffff)) * d2;
        acc[3] = bf2f((ushort)((unsigned)v.y >> 16)) * d2;
        acc[4] = bf2f((ushort)(v.z & 0xffff)) * d2;
        acc[5] = bf2f((ushort)((unsigned)v.z >> 16)) * d2;
        acc[6] = bf2f((ushort)(v.w & 0xffff)) * d2;
        acc[7] = bf2f((ushort)((unsigned)v.w >> 16)) * d2;
    }
    const int e = rowptr[node + 1];
    int j = rowptr[node] + g;
    int s_next = (j < e) ? esrc[j] : 0;
    for (; j < e; j += 4) {
        const int s = s_next;
        if (j + 4 < e) s_next = esrc[j + 4];
        const float nrm = dis[s] * dd;
        const int4 v = *(const int4*)(h + (size_t)s * 128 + sub * 8);
        acc[0] += bf2f((ushort)(v.x & 0xffff)) * nrm;
        acc[1] += bf2f((ushort)((unsigned)v.x >> 16)) * nrm;
        acc[2] += bf2f((ushort)(v.y & 0xffff)) * nrm;
        acc[3] += bf2f((ushort)((unsigned)v.y >> 16)) * nrm;
        acc[4] += bf2f((ushort)(v.z & 0xffff)) * nrm;
        acc[5] += bf2f((ushort)((unsigned)v.z >> 16)) * nrm;
        acc[6] += bf2f((ushort)(v.w & 0xffff)) * nrm;
        acc[7] += bf2f((ushort)((unsigned)v.w >> 16)) * nrm;
    }
#pragma unroll
    for (int i = 0; i < 8; ++i) {
        acc[i] += __shfl_xor(acc[i], 16);
        acc[i] += __shfl_xor(acc[i], 32);
    }
    if (g == 0) {
        int4 r;
        r.x = packbf(acc[0], acc[1]);
        r.y = packbf(acc[2], acc[3]);
        r.z = packbf(acc[4], acc[5]);
        r.w = packbf(acc[6], acc[7]);
        *(int4*)(out + (size_t)node * 128 + sub * 8) = r;
    }
}

// aggregate the 2 scalar cols (rw1, action); sources are L2-resident (200KB each)
__global__ void agg_ra(const float* __restrict__ rw1, const float* __restrict__ act,
                       float2* __restrict__ aggra,
                       const int* __restrict__ rowptr, const int* __restrict__ esrc,
                       const float* __restrict__ dis, int n)
{
    const int node = blockIdx.x * blockDim.x + threadIdx.x;
    if (node >= n) return;
    const float dd = dis[node];
    const float d2 = dd * dd;
    float a = rw1[node] * d2, b = act[node] * d2;
    const int e = rowptr[node + 1];
    for (int j = rowptr[node]; j < e; ++j) {
        const int s = esrc[j];
        const float nrm = dis[s] * dd;
        a += rw1[s] * nrm;
        b += act[s] * nrm;
    }
    aggra[node] = make_float2(a, b);
}

extern "C" void kernel_launch(void* const* d_in, const int* in_sizes, int n_in,
                              void* d_out, int out_size, void* d_ws, size_t ws_size,
                              hipStream_t stream)
{
    const float* x      = (const float*)d_in[0];
    const float* rw1    = (const float*)d_in[1];
    const float* action = (const float*)d_in[2];
    const float* noise  = (const float*)d_in[3];
    const int*   eidx   = (const int*)d_in[4];
    const float* W1     = (const float*)d_in[5];
    const float* b1     = (const float*)d_in[6];
    const float* Wg1    = (const float*)d_in[7];
    const float* bg1    = (const float*)d_in[8];
    const float* Whv    = (const float*)d_in[9];
    const float* bhv    = (const float*)d_in[10];
    const float* Wg2    = (const float*)d_in[11];
    const float* bg2    = (const float*)d_in[12];
    const int* src = eidx;
    const int* dst = eidx + NE;

    // Regions (u16 units), 12.8M each:
    // R0: tmp bf16 (ld 256)        R1: h -> hidden (ld 128, 6.4M)
    // R2: x3a (ld 256)             R3: aggcat -> agghid (ld 128, 6.4M)
    ushort* R0 = (ushort*)d_ws;
    ushort* R1 = R0 + 12800000;
    ushort* R2 = R1 + 12800000;
    ushort* R3 = R2 + 12800000;
    float* dis  = (float*)(R3 + 12800000);
    int* cnt    = (int*)(dis + NN);
    int* rowptr = cnt + NN;
    int* esrc   = rowptr + NN + 4;
    int* bsums  = esrc + NE;
    ushort* Wt1  = (ushort*)(bsums + 128); // [128][256]
    ushort* Wtg1 = Wt1 + 128 * 256;        // [256][160]
    ushort* Whvt = Wtg1 + 256 * 160;       // [256][256]
    ushort* Wg2t = Whvt + 256 * 256;       // [132][128]
    float2* aggra = (float2*)(Wg2t + 132 * 128);  // [NN]

    const int T = 256;
    const int gemmRows = (NN + 127) / 128;   // 391
    const int aggBlocks = (NN + 3) / 4;      // one wave per node
    const int scanBlocks = (NN + 511) / 512; // 98

    // ---- prep: weight transposes (one kernel) ----
    transpose_all<<<611, T, 0, stream>>>(W1, Wg1, Whv, Wg2, Wt1, Wtg1, Whvt, Wg2t);

    // ---- CSR build ----
    hipMemsetAsync(cnt, 0, NN * sizeof(int), stream);
    cnt_count<<<(NE + T - 1) / T, T, 0, stream>>>(cnt, dst, NE);
    scan_block_sums<<<scanBlocks, T, 0, stream>>>(cnt, bsums, NN);
    scan_small<<<1, T, 0, stream>>>(bsums, scanBlocks);
    scan_write<<<scanBlocks, T, 0, stream>>>(cnt, bsums, rowptr, dis, NN, NE);
    scatter_edges<<<(NE + T - 1) / T, T, 0, stream>>>(src, dst, cnt, esrc, NE);

    // ---- gemm1: relu(x@W1+b1) -> h bf16 (R1, ld 128) ----
    gemm_mfma<1, true, true, 1><<<dim3(gemmRows, 2), T, 0, stream>>>(
        x, 256, NN, nullptr, Wt1, 256, 264, 128, b1, R1, 128, 128);

    // ---- agg1 on h (128 cols) -> aggcat (R3, ld 128); rw/action separately ----
    agg128<<<aggBlocks, T, 0, stream>>>(R1, R3, rowptr, esrc, dis, NN);
    agg_ra<<<(NN + T - 1) / T, T, 0, stream>>>(rw1, action, aggra, rowptr, esrc, dis, NN);

    // ---- gemm2: relu([aggcat|aggra]@Wg1 + bg1) -> x3a bf16 (R2, ld 256) ----
    gemm_mfma<2, true, true, 1><<<dim3(gemmRows, 4), T, 0, stream>>>(
        R3, 128, NN, aggra, Wtg1, 160, 168, 256, bg1, R2, 256, 256);

    // ---- gemm3: relu(x3a@Whv+bhv) -> tmp bf16 (R0, ld 256) ----
    gemm_mfma<0, true, true, 1><<<dim3(gemmRows, 4), T, 0, stream>>>(
        R2, 256, NN, nullptr, Whvt, 256, 264, 256, bhv, R0, 256, 256);

    // ---- hidden (f32 math) -> bf16 (R1, ld 128) ----
    hidden_k<<<(NN * 32 + T - 1) / T, T, 0, stream>>>(R0, noise, R1, NN * 32);

    // ---- agg2 on hidden -> agghid (R3, ld 128) ----
    agg128<<<aggBlocks, T, 0, stream>>>(R1, R3, rowptr, esrc, dis, NN);

    // ---- gemm4: relu(agghid@Wg2 + bg2), fused split -> d_out ----
    gemm_mfma<0, true, true, 2><<<dim3(gemmRows, 3), T, 0, stream>>>(
        R3, 128, NN, nullptr, Wg2t, 128, 136, 129, bg2, d_out, 0, 129);
}

// Round 7
// 264.687 us; speedup vs baseline: 18.0807x; 1.2813x over previous
//
#include <hip/hip_runtime.h>

static constexpr int NN = 50000;   // nodes
static constexpr int NE = 800000;  // edges

typedef __attribute__((ext_vector_type(8))) short bf16x8;
typedef __attribute__((ext_vector_type(4))) float f32x4;

__device__ __forceinline__ float bf2f(ushort u) {
    union { unsigned int i; float f; } c; c.i = ((unsigned int)u) << 16; return c.f;
}
__device__ __forceinline__ ushort f2bf(float f) {
    union { float f; unsigned int i; } c; c.f = f;
    unsigned int x = c.i;
    return (ushort)((x + 0x7FFFu + ((x >> 16) & 1u)) >> 16);
}
__device__ __forceinline__ int packbf(float a, float b) {
    return (int)f2bf(a) | ((int)f2bf(b) << 16);
}

// ---------------- CSR build ----------------
__global__ void cnt_count(int* cnt, const int* __restrict__ dst, int e) {
    int i = blockIdx.x * blockDim.x + threadIdx.x;
    if (i < e) atomicAdd(&cnt[dst[i]], 1);
}

__global__ __launch_bounds__(256) void scan_block_sums(
    const int* __restrict__ cnt, int* __restrict__ blockSums, int n)
{
    __shared__ int sdata[256];
    const int base = blockIdx.x * 512;
    const int t = threadIdx.x;
    const int i0 = base + t * 2;
    int v = 0;
    if (i0 < n) v += cnt[i0];
    if (i0 + 1 < n) v += cnt[i0 + 1];
    sdata[t] = v;
    __syncthreads();
#pragma unroll
    for (int off = 128; off > 0; off >>= 1) {
        if (t < off) sdata[t] += sdata[t + off];
        __syncthreads();
    }
    if (t == 0) blockSums[blockIdx.x] = sdata[0];
}

__global__ __launch_bounds__(256) void scan_small(int* blockSums, int nb) {
    __shared__ int sdata[256];
    const int t = threadIdx.x;
    sdata[t] = (t < nb) ? blockSums[t] : 0;
    __syncthreads();
#pragma unroll
    for (int off = 1; off < 256; off <<= 1) {
        const int v = (t >= off) ? sdata[t - off] : 0;
        __syncthreads();
        sdata[t] += v;
        __syncthreads();
    }
    if (t < nb) blockSums[t] = (t == 0) ? 0 : sdata[t - 1];
}

// writes rowptr, cursor (=cnt, in place), dis
__global__ __launch_bounds__(256) void scan_write(
    int* __restrict__ cnt, const int* __restrict__ blockOffs,
    int* __restrict__ rowptr, float* __restrict__ dis, int n, int e)
{
    __shared__ int sdata[256];
    const int base = blockIdx.x * 512;
    const int t = threadIdx.x;
    const int i0 = base + t * 2;
    const int c0 = (i0 < n) ? cnt[i0] : 0;
    const int c1 = (i0 + 1 < n) ? cnt[i0 + 1] : 0;
    sdata[t] = c0 + c1;
    __syncthreads();
#pragma unroll
    for (int off = 1; off < 256; off <<= 1) {
        const int v = (t >= off) ? sdata[t - off] : 0;
        __syncthreads();
        sdata[t] += v;
        __syncthreads();
    }
    const int pre = blockOffs[blockIdx.x] + ((t == 0) ? 0 : sdata[t - 1]);
    if (i0 < n) {
        rowptr[i0] = pre; cnt[i0] = pre;
        dis[i0] = rsqrtf(1.0f + (float)c0);
    }
    if (i0 + 1 < n) {
        rowptr[i0 + 1] = pre + c0; cnt[i0 + 1] = pre + c0;
        dis[i0 + 1] = rsqrtf(1.0f + (float)c1);
    }
    if (blockIdx.x == 0 && t == 0) rowptr[n] = e;
}

__global__ void scatter_edges(const int* __restrict__ src, const int* __restrict__ dst,
                              int* cursor, ushort* __restrict__ esrc, int e) {
    int i = blockIdx.x * blockDim.x + threadIdx.x;
    if (i < e) {
        const int pos = atomicAdd(&cursor[dst[i]], 1);
        esrc[pos] = (ushort)src[i];   // node ids < 50000 < 65536
    }
}

// ---------------- prep: weight transposes + value-head weights ----------------
__global__ void transpose_all(const float* __restrict__ W1, const float* __restrict__ Wg1,
                              const float* __restrict__ Whv, const float* __restrict__ Wg2,
                              ushort* __restrict__ Wt1, ushort* __restrict__ Wtg1,
                              ushort* __restrict__ Whvt, ushort* __restrict__ Wg2t,
                              float* __restrict__ wval)
{
    int idx = blockIdx.x * blockDim.x + threadIdx.x;
    if (idx < 128 * 256) {                 // Wt1 [128][256] <- W1 [256][128]
        const int n = idx >> 8, k = idx & 255;
        Wt1[idx] = f2bf(W1[k * 128 + n]);
        return;
    }
    idx -= 128 * 256;
    if (idx < 256 * 160) {                 // Wtg1 [256][160] <- Wg1 [130][256]
        const int n = idx / 160, k = idx - n * 160;
        Wtg1[idx] = (k < 130) ? f2bf(Wg1[k * 256 + n]) : (ushort)0;
        return;
    }
    idx -= 256 * 160;
    if (idx < 256 * 256) {                 // Whvt [256][256] <- Whv [256][256]
        const int n = idx >> 8, k = idx & 255;
        Whvt[idx] = f2bf(Whv[k * 256 + n]);
        return;
    }
    idx -= 256 * 256;
    if (idx < 128 * 128) {                 // Wg2t [128][128] <- Wg2 [128][129] cols 0..127
        const int n = idx >> 7, k = idx & 127;
        Wg2t[idx] = f2bf(Wg2[k * 129 + n]);
        return;
    }
    idx -= 128 * 128;
    if (idx < 128) wval[idx] = Wg2[idx * 129 + 128];   // value column, f32
}

// ---------------- bf16 MFMA GEMM (512 thr, tile 128 x NB, K-sliced W) --------
// AMODE: 0 = A bf16, 1 = A f32 cast-on-stage, 2 = A bf16 + last K-slice
//        synthesized from aggra (k=128: rw, k=129: action, rest 0).
// C = relu(A @ Wt^T + bias); OUTF32 picks f32 vs bf16 store.
template<int AMODE, int K, int NB, bool OUTF32>
__global__ __launch_bounds__(512) void gemm_mfma(
    const void* __restrict__ Aptr, int lda, int M,
    const float2* __restrict__ aggra,
    const ushort* __restrict__ Wt,
    const float* __restrict__ bias,
    void* __restrict__ Cout, int ldc)
{
    constexpr int NK = K / 32;
    constexpr int CF = NB / 64;        // col frags per wave (2 or 4)
    __shared__ ushort A_s[2][128 * 40];
    __shared__ ushort W_s[2][NB * 40];

    const int tid  = threadIdx.x;
    const int row0 = blockIdx.x * 128;
    const int lane = tid & 63;
    const int wid  = tid >> 6;
    const int wr = wid >> 2;           // 0..1 (row half)
    const int wc = wid & 3;            // 0..3 (col quarter)
    const int lr = lane & 15;
    const int kg = lane >> 4;

    // staging: thread t covers A row t>>2, 8-elem chunk (t&3)*8 of each 32-K slice
    const int sr = tid >> 2;
    const int sc = (tid & 3) * 8;
    const bool rok = (row0 + sr) < M;
    const ushort* Agu = (const ushort*)Aptr + (size_t)(row0 + sr) * lda + sc;
    const float*  Agf = (const float*)Aptr + (size_t)(row0 + sr) * lda + sc;
    const ushort* Wg0 = Wt + (size_t)sr * K + sc;            // W row sr
    const ushort* Wg1p = Wt + (size_t)(sr + 128) * K + sc;   // W row sr+128 (NB=256)

    int4 sa = make_int4(0,0,0,0), sw0 = sa, sw1 = sa;
    auto load_A = [&](int kk) {
        if (AMODE == 2 && kk == NK - 1) {
            sa = make_int4(0, 0, 0, 0);
            if (sc == 0 && rok) {
                const float2 ra = aggra[row0 + sr];
                sa.x = packbf(ra.x, ra.y);
            }
        } else if (AMODE == 1) {
            if (rok) {
                const float* p = Agf + kk * 32;
                const float4 f0 = *(const float4*)(p + 0);
                const float4 f1 = *(const float4*)(p + 4);
                sa.x = packbf(f0.x, f0.y); sa.y = packbf(f0.z, f0.w);
                sa.z = packbf(f1.x, f1.y); sa.w = packbf(f1.z, f1.w);
            } else sa = make_int4(0, 0, 0, 0);
        } else {
            sa = rok ? *(const int4*)(Agu + kk * 32) : make_int4(0, 0, 0, 0);
        }
    };
    auto load_W = [&](int kk) {
        sw0 = *(const int4*)(Wg0 + kk * 32);
        if constexpr (NB == 256) sw1 = *(const int4*)(Wg1p + kk * 32);
    };
    auto store_A = [&](int buf) { *(int4*)&A_s[buf][sr * 40 + sc] = sa; };
    auto store_W = [&](int buf) {
        *(int4*)&W_s[buf][sr * 40 + sc] = sw0;
        if constexpr (NB == 256) *(int4*)&W_s[buf][(sr + 128) * 40 + sc] = sw1;
    };

    load_A(0); load_W(0);
    store_A(0); store_W(0);

    f32x4 acc[4][CF];
#pragma unroll
    for (int m = 0; m < 4; ++m)
#pragma unroll
        for (int n = 0; n < CF; ++n) acc[m][n] = (f32x4){0.f, 0.f, 0.f, 0.f};

    const int abase = (wr * 64 + lr) * 40 + kg * 8;
    const int bbase = (wc * (NB / 4) + lr) * 40 + kg * 8;

    for (int kk = 0; kk < NK; ++kk) {
        if (kk + 1 < NK) { load_A(kk + 1); load_W(kk + 1); }
        __syncthreads();
        const ushort* Ab = A_s[kk & 1];
        const ushort* Wb = W_s[kk & 1];
        bf16x8 a[4], b[CF];
#pragma unroll
        for (int m = 0; m < 4; ++m) a[m] = *(const bf16x8*)&Ab[abase + m * 16 * 40];
#pragma unroll
        for (int n = 0; n < CF; ++n) b[n] = *(const bf16x8*)&Wb[bbase + n * 16 * 40];
#pragma unroll
        for (int m = 0; m < 4; ++m)
#pragma unroll
            for (int n = 0; n < CF; ++n)
                acc[m][n] = __builtin_amdgcn_mfma_f32_16x16x32_bf16(a[m], b[n], acc[m][n], 0, 0, 0);
        if (kk + 1 < NK) { store_A((kk + 1) & 1); store_W((kk + 1) & 1); }
    }

    // epilogue: C/D layout col=lane&15, row=(lane>>4)*4+r
#pragma unroll
    for (int m = 0; m < 4; ++m) {
#pragma unroll
        for (int n = 0; n < CF; ++n) {
            const int c = wc * (NB / 4) + n * 16 + lr;
            const float bb = bias[c];
            const int r0 = row0 + wr * 64 + m * 16 + kg * 4;
#pragma unroll
            for (int r = 0; r < 4; ++r) {
                const int R = r0 + r;
                if (R >= M) continue;
                const float v = fmaxf(acc[m][n][r] + bb, 0.f);
                if (OUTF32) ((float*)Cout)[(size_t)R * ldc + c] = v;
                else        ((ushort*)Cout)[(size_t)R * ldc + c] = f2bf(v);
            }
        }
    }
}

// ---------------- glue ----------------
// hidden = mean + noise*exp(clip(logvar,-5,5)); tmp bf16 ld 256 -> hidden bf16 ld 128
__global__ void hidden_k(const ushort* __restrict__ tmp, const float* __restrict__ noise,
                         ushort* __restrict__ hid, int n32) {
    int i = blockIdx.x * blockDim.x + threadIdx.x;
    if (i >= n32) return;
    const int row = i >> 5, c4 = (i & 31) * 4;
    const ushort4 mu = *(const ushort4*)(tmp + (size_t)row * 256 + c4);
    const ushort4 lg = *(const ushort4*)(tmp + (size_t)row * 256 + 128 + c4);
    const float4 nz = *(const float4*)(noise + (size_t)row * 128 + c4);
    ushort4 r;
    r.x = f2bf(bf2f(mu.x) + nz.x * expf(fminf(fmaxf(bf2f(lg.x), -5.f), 5.f)));
    r.y = f2bf(bf2f(mu.y) + nz.y * expf(fminf(fmaxf(bf2f(lg.y), -5.f), 5.f)));
    r.z = f2bf(bf2f(mu.z) + nz.z * expf(fminf(fmaxf(bf2f(lg.z), -5.f), 5.f)));
    r.w = f2bf(bf2f(mu.w) + nz.w * expf(fminf(fmaxf(bf2f(lg.w), -5.f), 5.f)));
    *(ushort4*)(hid + (size_t)row * 128 + c4) = r;
}

// ---------------- CSR gather aggregation, 128-col bf16 rows ----------------
// One wave per node; 16 lanes x int4 per edge row, 4 edges in flight; butterfly
// reduce across edge groups. VAL: fuse value head (agghid . wval + b, relu).
template<bool VAL>
__global__ __launch_bounds__(256) void agg128(
    const ushort* __restrict__ h, ushort* __restrict__ out,
    const int* __restrict__ rowptr, const ushort* __restrict__ esrc,
    const float* __restrict__ dis, int n,
    const float* __restrict__ wval, const float* __restrict__ bg2,
    float* __restrict__ vout)
{
    const int node = (blockIdx.x * blockDim.x + threadIdx.x) >> 6;
    if (node >= n) return;
    const int lane = threadIdx.x & 63;
    const int g = lane >> 4;        // edge group 0..3
    const int sub = lane & 15;      // 8-col chunk
    const float dd = dis[node];

    float acc[8] = {0.f, 0.f, 0.f, 0.f, 0.f, 0.f, 0.f, 0.f};
    if (g == 0) {   // self loop, counted once
        const int4 v = *(const int4*)(h + (size_t)node * 128 + sub * 8);
        const float d2 = dd * dd;
        acc[0] = bf2f((ushort)(v.x & 0xffff)) * d2;
        acc[1] = bf2f((ushort)((unsigned)v.x >> 16)) * d2;
        acc[2] = bf2f((ushort)(v.y & 0xffff)) * d2;
        acc[3] = bf2f((ushort)((unsigned)v.y >> 16)) * d2;
        acc[4] = bf2f((ushort)(v.z & 0xffff)) * d2;
        acc[5] = bf2f((ushort)((unsigned)v.z >> 16)) * d2;
        acc[6] = bf2f((ushort)(v.w & 0xffff)) * d2;
        acc[7] = bf2f((ushort)((unsigned)v.w >> 16)) * d2;
    }
    const int e = rowptr[node + 1];
    int j = rowptr[node] + g;
    int s_next = (j < e) ? (int)esrc[j] : 0;
    for (; j < e; j += 4) {
        const int s = s_next;
        if (j + 4 < e) s_next = (int)esrc[j + 4];
        const float nrm = dis[s] * dd;
        const int4 v = *(const int4*)(h + (size_t)s * 128 + sub * 8);
        acc[0] += bf2f((ushort)(v.x & 0xffff)) * nrm;
        acc[1] += bf2f((ushort)((unsigned)v.x >> 16)) * nrm;
        acc[2] += bf2f((ushort)(v.y & 0xffff)) * nrm;
        acc[3] += bf2f((ushort)((unsigned)v.y >> 16)) * nrm;
        acc[4] += bf2f((ushort)(v.z & 0xffff)) * nrm;
        acc[5] += bf2f((ushort)((unsigned)v.z >> 16)) * nrm;
        acc[6] += bf2f((ushort)(v.w & 0xffff)) * nrm;
        acc[7] += bf2f((ushort)((unsigned)v.w >> 16)) * nrm;
    }
#pragma unroll
    for (int i = 0; i < 8; ++i) {
        acc[i] += __shfl_xor(acc[i], 16);
        acc[i] += __shfl_xor(acc[i], 32);
    }
    if (g == 0) {
        int4 r;
        r.x = packbf(acc[0], acc[1]);
        r.y = packbf(acc[2], acc[3]);
        r.z = packbf(acc[4], acc[5]);
        r.w = packbf(acc[6], acc[7]);
        *(int4*)(out + (size_t)node * 128 + sub * 8) = r;
    }
    if (VAL) {   // fused value head on f32 accumulators
        float va = 0.f;
#pragma unroll
        for (int i = 0; i < 8; ++i) va += acc[i] * wval[sub * 8 + i];
        va += __shfl_xor(va, 1);
        va += __shfl_xor(va, 2);
        va += __shfl_xor(va, 4);
        va += __shfl_xor(va, 8);
        if (lane == 0) vout[node] = fmaxf(va + bg2[128], 0.f);
    }
}

// aggregate the 2 scalar cols (rw1, action); sources are L2-resident
__global__ void agg_ra(const float* __restrict__ rw1, const float* __restrict__ act,
                       float2* __restrict__ aggra,
                       const int* __restrict__ rowptr, const ushort* __restrict__ esrc,
                       const float* __restrict__ dis, int n)
{
    const int node = blockIdx.x * blockDim.x + threadIdx.x;
    if (node >= n) return;
    const float dd = dis[node];
    const float d2 = dd * dd;
    float a = rw1[node] * d2, b = act[node] * d2;
    const int e = rowptr[node + 1];
    for (int j = rowptr[node]; j < e; ++j) {
        const int s = (int)esrc[j];
        const float nrm = dis[s] * dd;
        a += rw1[s] * nrm;
        b += act[s] * nrm;
    }
    aggra[node] = make_float2(a, b);
}

extern "C" void kernel_launch(void* const* d_in, const int* in_sizes, int n_in,
                              void* d_out, int out_size, void* d_ws, size_t ws_size,
                              hipStream_t stream)
{
    const float* x      = (const float*)d_in[0];
    const float* rw1    = (const float*)d_in[1];
    const float* action = (const float*)d_in[2];
    const float* noise  = (const float*)d_in[3];
    const int*   eidx   = (const int*)d_in[4];
    const float* W1     = (const float*)d_in[5];
    const float* b1     = (const float*)d_in[6];
    const float* Wg1    = (const float*)d_in[7];
    const float* bg1    = (const float*)d_in[8];
    const float* Whv    = (const float*)d_in[9];
    const float* bhv    = (const float*)d_in[10];
    const float* Wg2    = (const float*)d_in[11];
    const float* bg2    = (const float*)d_in[12];
    const int* src = eidx;
    const int* dst = eidx + NE;

    // Regions (u16 units), 12.8M each:
    // R0: tmp bf16 (ld 256)        R1: h -> hidden (ld 128, 6.4M)
    // R2: x3a (ld 256)             R3: aggcat -> agghid (ld 128, 6.4M)
    ushort* R0 = (ushort*)d_ws;
    ushort* R1 = R0 + 12800000;
    ushort* R2 = R1 + 12800000;
    ushort* R3 = R2 + 12800000;
    float* dis  = (float*)(R3 + 12800000);
    int* cnt    = (int*)(dis + NN);
    int* rowptr = cnt + NN;
    ushort* esrc = (ushort*)(rowptr + NN + 4);   // u16 src ids
    int* bsums  = (int*)(esrc + NE);
    ushort* Wt1  = (ushort*)(bsums + 128); // [128][256]
    ushort* Wtg1 = Wt1 + 128 * 256;        // [256][160]
    ushort* Whvt = Wtg1 + 256 * 160;       // [256][256]
    ushort* Wg2t = Whvt + 256 * 256;       // [128][128]
    float* wval  = (float*)(Wg2t + 128 * 128);   // [128]
    float2* aggra = (float2*)(wval + 128);       // [NN]

    const int T = 256;
    const int gemmRows = (NN + 127) / 128;   // 391
    const int aggBlocks = (NN + 3) / 4;      // one wave per node
    const int scanBlocks = (NN + 511) / 512; // 98

    // ---- prep: weight transposes (one kernel) ----
    transpose_all<<<609, T, 0, stream>>>(W1, Wg1, Whv, Wg2, Wt1, Wtg1, Whvt, Wg2t, wval);

    // ---- CSR build ----
    hipMemsetAsync(cnt, 0, NN * sizeof(int), stream);
    cnt_count<<<(NE + T - 1) / T, T, 0, stream>>>(cnt, dst, NE);
    scan_block_sums<<<scanBlocks, T, 0, stream>>>(cnt, bsums, NN);
    scan_small<<<1, T, 0, stream>>>(bsums, scanBlocks);
    scan_write<<<scanBlocks, T, 0, stream>>>(cnt, bsums, rowptr, dis, NN, NE);
    scatter_edges<<<(NE + T - 1) / T, T, 0, stream>>>(src, dst, cnt, esrc, NE);

    // ---- gemm1: relu(x@W1+b1) -> h bf16 (R1, ld 128); A = f32 x ----
    gemm_mfma<1, 256, 128, false><<<gemmRows, 512, 0, stream>>>(
        x, 256, NN, nullptr, Wt1, b1, R1, 128);

    // ---- agg1 on h -> aggcat (R3, ld 128); rw/action separately ----
    agg128<false><<<aggBlocks, T, 0, stream>>>(R1, R3, rowptr, esrc, dis, NN,
                                               nullptr, nullptr, nullptr);
    agg_ra<<<(NN + T - 1) / T, T, 0, stream>>>(rw1, action, aggra, rowptr, esrc, dis, NN);

    // ---- gemm2: relu([aggcat|aggra]@Wg1 + bg1) -> x3a bf16 (R2, ld 256) ----
    gemm_mfma<2, 160, 256, false><<<gemmRows, 512, 0, stream>>>(
        R3, 128, NN, aggra, Wtg1, bg1, R2, 256);

    // ---- gemm3: relu(x3a@Whv+bhv) -> tmp bf16 (R0, ld 256) ----
    gemm_mfma<0, 256, 256, false><<<gemmRows, 512, 0, stream>>>(
        R2, 256, NN, nullptr, Whvt, bhv, R0, 256);

    // ---- hidden (f32 math) -> bf16 (R1, ld 128) ----
    hidden_k<<<(NN * 32 + T - 1) / T, T, 0, stream>>>(R0, noise, R1, NN * 32);

    // ---- agg2 on hidden -> agghid (R3, ld 128) + fused value head -> d_out tail ----
    agg128<true><<<aggBlocks, T, 0, stream>>>(R1, R3, rowptr, esrc, dis, NN,
                                              wval, bg2, (float*)d_out + (size_t)NN * 128);

    // ---- gemm4: relu(agghid@Wg2 + bg2) cols 0..127 -> d_out f32 ld 128 ----
    gemm_mfma<0, 128, 128, true><<<gemmRows, 512, 0, stream>>>(
        R3, 128, NN, nullptr, Wg2t, bg2, d_out, 128);
}

// Round 8
// 222.353 us; speedup vs baseline: 21.5231x; 1.1904x over previous
//
#include <hip/hip_runtime.h>

static constexpr int NN = 50000;   // nodes
static constexpr int NE = 800000;  // edges
static constexpr int NBUCK = (NN + 127) / 128;  // 391 buckets (dst >> 7)
static constexpr int CAP = 4096;   // staging capacity per bucket (avg 2046, max ~2350)

typedef __attribute__((ext_vector_type(8))) short bf16x8;
typedef __attribute__((ext_vector_type(4))) float f32x4;

__device__ __forceinline__ float bf2f(ushort u) {
    union { unsigned int i; float f; } c; c.i = ((unsigned int)u) << 16; return c.f;
}
__device__ __forceinline__ ushort f2bf(float f) {
    union { float f; unsigned int i; } c; c.f = f;
    unsigned int x = c.i;
    return (ushort)((x + 0x7FFFu + ((x >> 16) & 1u)) >> 16);
}
__device__ __forceinline__ int packbf(float a, float b) {
    return (int)f2bf(a) | ((int)f2bf(b) << 16);
}

// ---------------- bucketed CSR build ----------------
// Phase A: partition edges into 391 dst-buckets; per-block LDS histogram +
// one reservation atomic per (block,bucket); staged writes are near-sequential.
__global__ __launch_bounds__(256) void bucket_edges(
    const int* __restrict__ src, const int* __restrict__ dst,
    int* __restrict__ bcur, unsigned* __restrict__ staging, int e)
{
    __shared__ int bins[NBUCK];
    __shared__ int gbase[NBUCK];
    __shared__ int cur[NBUCK];
    const int t = threadIdx.x;
    const int base = blockIdx.x * 8192;
    for (int i = t; i < NBUCK; i += 256) bins[i] = 0;
    __syncthreads();
    const int lim = min(8192, e - base);
    for (int i = t; i < lim; i += 256)
        atomicAdd(&bins[dst[base + i] >> 7], 1);
    __syncthreads();
    for (int i = t; i < NBUCK; i += 256) {
        cur[i] = 0;
        gbase[i] = bins[i] ? atomicAdd(&bcur[i], bins[i]) : 0;
    }
    __syncthreads();
    for (int i = t; i < lim; i += 256) {
        const int d = dst[base + i];
        const int b = d >> 7;
        const int r = atomicAdd(&cur[b], 1);
        staging[(size_t)b * CAP + gbase[b] + r] =
            ((unsigned)(d & 127) << 16) | (unsigned)src[base + i];
    }
}

// Phase B: per-bucket histogram -> cnt (plain stores, no global atomics)
__global__ __launch_bounds__(128) void hist_bucket(
    const unsigned* __restrict__ staging, const int* __restrict__ bcur,
    int* __restrict__ cnt, int n)
{
    __shared__ int bins[128];
    const int b = blockIdx.x;
    const int t = threadIdx.x;
    bins[t] = 0;
    __syncthreads();
    const int m = bcur[b];
    const unsigned* sp = staging + (size_t)b * CAP;
    for (int i = t; i < m; i += 128) atomicAdd(&bins[sp[i] >> 16], 1);
    __syncthreads();
    const int node = (b << 7) + t;
    if (node < n) cnt[node] = bins[t];
}

__global__ __launch_bounds__(256) void scan_block_sums(
    const int* __restrict__ cnt, int* __restrict__ blockSums, int n)
{
    __shared__ int sdata[256];
    const int base = blockIdx.x * 512;
    const int t = threadIdx.x;
    const int i0 = base + t * 2;
    int v = 0;
    if (i0 < n) v += cnt[i0];
    if (i0 + 1 < n) v += cnt[i0 + 1];
    sdata[t] = v;
    __syncthreads();
#pragma unroll
    for (int off = 128; off > 0; off >>= 1) {
        if (t < off) sdata[t] += sdata[t + off];
        __syncthreads();
    }
    if (t == 0) blockSums[blockIdx.x] = sdata[0];
}

__global__ __launch_bounds__(256) void scan_small(int* blockSums, int nb) {
    __shared__ int sdata[256];
    const int t = threadIdx.x;
    sdata[t] = (t < nb) ? blockSums[t] : 0;
    __syncthreads();
#pragma unroll
    for (int off = 1; off < 256; off <<= 1) {
        const int v = (t >= off) ? sdata[t - off] : 0;
        __syncthreads();
        sdata[t] += v;
        __syncthreads();
    }
    if (t < nb) blockSums[t] = (t == 0) ? 0 : sdata[t - 1];
}

// writes rowptr + dis
__global__ __launch_bounds__(256) void scan_write(
    const int* __restrict__ cnt, const int* __restrict__ blockOffs,
    int* __restrict__ rowptr, float* __restrict__ dis, int n, int e)
{
    __shared__ int sdata[256];
    const int base = blockIdx.x * 512;
    const int t = threadIdx.x;
    const int i0 = base + t * 2;
    const int c0 = (i0 < n) ? cnt[i0] : 0;
    const int c1 = (i0 + 1 < n) ? cnt[i0 + 1] : 0;
    sdata[t] = c0 + c1;
    __syncthreads();
#pragma unroll
    for (int off = 1; off < 256; off <<= 1) {
        const int v = (t >= off) ? sdata[t - off] : 0;
        __syncthreads();
        sdata[t] += v;
        __syncthreads();
    }
    const int pre = blockOffs[blockIdx.x] + ((t == 0) ? 0 : sdata[t - 1]);
    if (i0 < n)     { rowptr[i0] = pre;          dis[i0] = rsqrtf(1.0f + (float)c0); }
    if (i0 + 1 < n) { rowptr[i0 + 1] = pre + c0; dis[i0 + 1] = rsqrtf(1.0f + (float)c1); }
    if (blockIdx.x == 0 && t == 0) rowptr[n] = e;
}

// Phase C: sort within bucket via LDS counting sort; esrc written coalesced.
__global__ __launch_bounds__(128) void sort_bucket(
    const unsigned* __restrict__ staging, const int* __restrict__ bcur,
    const int* __restrict__ rowptr, ushort* __restrict__ esrc)
{
    __shared__ int bins[128];
    __shared__ int sdata[128];
    __shared__ ushort outb[CAP];
    const int b = blockIdx.x;
    const int t = threadIdx.x;
    bins[t] = 0;
    __syncthreads();
    const int m = bcur[b];
    const unsigned* sp = staging + (size_t)b * CAP;
    for (int i = t; i < m; i += 128) atomicAdd(&bins[sp[i] >> 16], 1);
    __syncthreads();
    const int v = bins[t];
    sdata[t] = v;
    __syncthreads();
#pragma unroll
    for (int off = 1; off < 128; off <<= 1) {
        const int u = (t >= off) ? sdata[t - off] : 0;
        __syncthreads();
        sdata[t] += u;
        __syncthreads();
    }
    bins[t] = sdata[t] - v;   // exclusive prefix -> cursor
    __syncthreads();
    for (int i = t; i < m; i += 128) {
        const unsigned p = sp[i];
        const int r = atomicAdd(&bins[p >> 16], 1);
        outb[r] = (ushort)(p & 0xffffu);
    }
    __syncthreads();
    const int ebase = rowptr[b << 7];
    for (int i = t; i < m; i += 128) esrc[ebase + i] = outb[i];
}

// ---------------- prep: weight transposes + value-head weights ----------------
__global__ void transpose_all(const float* __restrict__ W1, const float* __restrict__ Wg1,
                              const float* __restrict__ Whv, const float* __restrict__ Wg2,
                              ushort* __restrict__ Wt1, ushort* __restrict__ Wtg1,
                              ushort* __restrict__ Whvt, ushort* __restrict__ Wg2t,
                              float* __restrict__ wval)
{
    int idx = blockIdx.x * blockDim.x + threadIdx.x;
    if (idx < 128 * 256) {                 // Wt1 [128][256] <- W1 [256][128]
        const int n = idx >> 8, k = idx & 255;
        Wt1[idx] = f2bf(W1[k * 128 + n]);
        return;
    }
    idx -= 128 * 256;
    if (idx < 256 * 160) {                 // Wtg1 [256][160] <- Wg1 [130][256]
        const int n = idx / 160, k = idx - n * 160;
        Wtg1[idx] = (k < 130) ? f2bf(Wg1[k * 256 + n]) : (ushort)0;
        return;
    }
    idx -= 256 * 160;
    if (idx < 256 * 256) {                 // Whvt [256][256] <- Whv [256][256]
        const int n = idx >> 8, k = idx & 255;
        Whvt[idx] = f2bf(Whv[k * 256 + n]);
        return;
    }
    idx -= 256 * 256;
    if (idx < 128 * 128) {                 // Wg2t [128][128] <- Wg2 [128][129] cols 0..127
        const int n = idx >> 7, k = idx & 127;
        Wg2t[idx] = f2bf(Wg2[k * 129 + n]);
        return;
    }
    idx -= 128 * 128;
    if (idx < 128) wval[idx] = Wg2[idx * 129 + 128];   // value column, f32
}

// ---------------- bf16 MFMA GEMM (512 thr, tile 128 x NB, K-sliced W) --------
template<int AMODE, int K, int NB, bool OUTF32>
__global__ __launch_bounds__(512) void gemm_mfma(
    const void* __restrict__ Aptr, int lda, int M,
    const float2* __restrict__ aggra,
    const ushort* __restrict__ Wt,
    const float* __restrict__ bias,
    void* __restrict__ Cout, int ldc)
{
    constexpr int NK = K / 32;
    constexpr int CF = NB / 64;        // col frags per wave (2 or 4)
    __shared__ ushort A_s[2][128 * 40];
    __shared__ ushort W_s[2][NB * 40];

    const int tid  = threadIdx.x;
    const int row0 = blockIdx.x * 128;
    const int lane = tid & 63;
    const int wid  = tid >> 6;
    const int wr = wid >> 2;
    const int wc = wid & 3;
    const int lr = lane & 15;
    const int kg = lane >> 4;

    const int sr = tid >> 2;
    const int sc = (tid & 3) * 8;
    const bool rok = (row0 + sr) < M;
    const ushort* Agu = (const ushort*)Aptr + (size_t)(row0 + sr) * lda + sc;
    const float*  Agf = (const float*)Aptr + (size_t)(row0 + sr) * lda + sc;
    const ushort* Wg0 = Wt + (size_t)sr * K + sc;
    const ushort* Wg1p = Wt + (size_t)(sr + 128) * K + sc;

    int4 sa = make_int4(0,0,0,0), sw0 = sa, sw1 = sa;
    auto load_A = [&](int kk) {
        if (AMODE == 2 && kk == NK - 1) {
            sa = make_int4(0, 0, 0, 0);
            if (sc == 0 && rok) {
                const float2 ra = aggra[row0 + sr];
                sa.x = packbf(ra.x, ra.y);
            }
        } else if (AMODE == 1) {
            if (rok) {
                const float* p = Agf + kk * 32;
                const float4 f0 = *(const float4*)(p + 0);
                const float4 f1 = *(const float4*)(p + 4);
                sa.x = packbf(f0.x, f0.y); sa.y = packbf(f0.z, f0.w);
                sa.z = packbf(f1.x, f1.y); sa.w = packbf(f1.z, f1.w);
            } else sa = make_int4(0, 0, 0, 0);
        } else {
            sa = rok ? *(const int4*)(Agu + kk * 32) : make_int4(0, 0, 0, 0);
        }
    };
    auto load_W = [&](int kk) {
        sw0 = *(const int4*)(Wg0 + kk * 32);
        if constexpr (NB == 256) sw1 = *(const int4*)(Wg1p + kk * 32);
    };
    auto store_A = [&](int buf) { *(int4*)&A_s[buf][sr * 40 + sc] = sa; };
    auto store_W = [&](int buf) {
        *(int4*)&W_s[buf][sr * 40 + sc] = sw0;
        if constexpr (NB == 256) *(int4*)&W_s[buf][(sr + 128) * 40 + sc] = sw1;
    };

    load_A(0); load_W(0);
    store_A(0); store_W(0);

    f32x4 acc[4][CF];
#pragma unroll
    for (int m = 0; m < 4; ++m)
#pragma unroll
        for (int n = 0; n < CF; ++n) acc[m][n] = (f32x4){0.f, 0.f, 0.f, 0.f};

    const int abase = (wr * 64 + lr) * 40 + kg * 8;
    const int bbase = (wc * (NB / 4) + lr) * 40 + kg * 8;

    for (int kk = 0; kk < NK; ++kk) {
        if (kk + 1 < NK) { load_A(kk + 1); load_W(kk + 1); }
        __syncthreads();
        const ushort* Ab = A_s[kk & 1];
        const ushort* Wb = W_s[kk & 1];
        bf16x8 a[4], b[CF];
#pragma unroll
        for (int m = 0; m < 4; ++m) a[m] = *(const bf16x8*)&Ab[abase + m * 16 * 40];
#pragma unroll
        for (int n = 0; n < CF; ++n) b[n] = *(const bf16x8*)&Wb[bbase + n * 16 * 40];
#pragma unroll
        for (int m = 0; m < 4; ++m)
#pragma unroll
            for (int n = 0; n < CF; ++n)
                acc[m][n] = __builtin_amdgcn_mfma_f32_16x16x32_bf16(a[m], b[n], acc[m][n], 0, 0, 0);
        if (kk + 1 < NK) { store_A((kk + 1) & 1); store_W((kk + 1) & 1); }
    }

#pragma unroll
    for (int m = 0; m < 4; ++m) {
#pragma unroll
        for (int n = 0; n < CF; ++n) {
            const int c = wc * (NB / 4) + n * 16 + lr;
            const float bb = bias[c];
            const int r0 = row0 + wr * 64 + m * 16 + kg * 4;
#pragma unroll
            for (int r = 0; r < 4; ++r) {
                const int R = r0 + r;
                if (R >= M) continue;
                const float v = fmaxf(acc[m][n][r] + bb, 0.f);
                if (OUTF32) ((float*)Cout)[(size_t)R * ldc + c] = v;
                else        ((ushort*)Cout)[(size_t)R * ldc + c] = f2bf(v);
            }
        }
    }
}

// ---------------- glue ----------------
__global__ void hidden_k(const ushort* __restrict__ tmp, const float* __restrict__ noise,
                         ushort* __restrict__ hid, int n32) {
    int i = blockIdx.x * blockDim.x + threadIdx.x;
    if (i >= n32) return;
    const int row = i >> 5, c4 = (i & 31) * 4;
    const ushort4 mu = *(const ushort4*)(tmp + (size_t)row * 256 + c4);
    const ushort4 lg = *(const ushort4*)(tmp + (size_t)row * 256 + 128 + c4);
    const float4 nz = *(const float4*)(noise + (size_t)row * 128 + c4);
    ushort4 r;
    r.x = f2bf(bf2f(mu.x) + nz.x * expf(fminf(fmaxf(bf2f(lg.x), -5.f), 5.f)));
    r.y = f2bf(bf2f(mu.y) + nz.y * expf(fminf(fmaxf(bf2f(lg.y), -5.f), 5.f)));
    r.z = f2bf(bf2f(mu.z) + nz.z * expf(fminf(fmaxf(bf2f(lg.z), -5.f), 5.f)));
    r.w = f2bf(bf2f(mu.w) + nz.w * expf(fminf(fmaxf(bf2f(lg.w), -5.f), 5.f)));
    *(ushort4*)(hid + (size_t)row * 128 + c4) = r;
}

// ---------------- CSR gather aggregation, 128-col bf16 rows ----------------
// RA: fuse rw1/action aggregation (agg1). VAL: fuse value head (agg2).
template<bool RA, bool VAL>
__global__ __launch_bounds__(256) void agg128(
    const ushort* __restrict__ h, ushort* __restrict__ out,
    const int* __restrict__ rowptr, const ushort* __restrict__ esrc,
    const float* __restrict__ dis, int n,
    const float* __restrict__ rw1, const float* __restrict__ act,
    float2* __restrict__ aggra,
    const float* __restrict__ wval, const float* __restrict__ bg2,
    float* __restrict__ vout)
{
    const int node = (blockIdx.x * blockDim.x + threadIdx.x) >> 6;
    if (node >= n) return;
    const int lane = threadIdx.x & 63;
    const int g = lane >> 4;        // edge group 0..3
    const int sub = lane & 15;      // 8-col chunk
    const float dd = dis[node];

    float acc[8] = {0.f, 0.f, 0.f, 0.f, 0.f, 0.f, 0.f, 0.f};
    float ra_a = 0.f, ra_b = 0.f;
    if (g == 0) {   // self loop, counted once
        const int4 v = *(const int4*)(h + (size_t)node * 128 + sub * 8);
        const float d2 = dd * dd;
        acc[0] = bf2f((ushort)(v.x & 0xffff)) * d2;
        acc[1] = bf2f((ushort)((unsigned)v.x >> 16)) * d2;
        acc[2] = bf2f((ushort)(v.y & 0xffff)) * d2;
        acc[3] = bf2f((ushort)((unsigned)v.y >> 16)) * d2;
        acc[4] = bf2f((ushort)(v.z & 0xffff)) * d2;
        acc[5] = bf2f((ushort)((unsigned)v.z >> 16)) * d2;
        acc[6] = bf2f((ushort)(v.w & 0xffff)) * d2;
        acc[7] = bf2f((ushort)((unsigned)v.w >> 16)) * d2;
        if (RA && sub == 0) { ra_a = rw1[node] * d2; ra_b = act[node] * d2; }
    }
    const int e = rowptr[node + 1];
    int j = rowptr[node] + g;
    int s_next = (j < e) ? (int)esrc[j] : 0;
    for (; j < e; j += 4) {
        const int s = s_next;
        if (j + 4 < e) s_next = (int)esrc[j + 4];
        const float nrm = dis[s] * dd;
        const int4 v = *(const int4*)(h + (size_t)s * 128 + sub * 8);
        acc[0] += bf2f((ushort)(v.x & 0xffff)) * nrm;
        acc[1] += bf2f((ushort)((unsigned)v.x >> 16)) * nrm;
        acc[2] += bf2f((ushort)(v.y & 0xffff)) * nrm;
        acc[3] += bf2f((ushort)((unsigned)v.y >> 16)) * nrm;
        acc[4] += bf2f((ushort)(v.z & 0xffff)) * nrm;
        acc[5] += bf2f((ushort)((unsigned)v.z >> 16)) * nrm;
        acc[6] += bf2f((ushort)(v.w & 0xffff)) * nrm;
        acc[7] += bf2f((ushort)((unsigned)v.w >> 16)) * nrm;
        if (RA && sub == 0) { ra_a += rw1[s] * nrm; ra_b += act[s] * nrm; }
    }
#pragma unroll
    for (int i = 0; i < 8; ++i) {
        acc[i] += __shfl_xor(acc[i], 16);
        acc[i] += __shfl_xor(acc[i], 32);
    }
    if (RA) {
        ra_a += __shfl_xor(ra_a, 16); ra_a += __shfl_xor(ra_a, 32);
        ra_b += __shfl_xor(ra_b, 16); ra_b += __shfl_xor(ra_b, 32);
        if (lane == 0) aggra[node] = make_float2(ra_a, ra_b);
    }
    if (g == 0) {
        int4 r;
        r.x = packbf(acc[0], acc[1]);
        r.y = packbf(acc[2], acc[3]);
        r.z = packbf(acc[4], acc[5]);
        r.w = packbf(acc[6], acc[7]);
        *(int4*)(out + (size_t)node * 128 + sub * 8) = r;
    }
    if (VAL) {   // fused value head on f32 accumulators
        float va = 0.f;
#pragma unroll
        for (int i = 0; i < 8; ++i) va += acc[i] * wval[sub * 8 + i];
        va += __shfl_xor(va, 1);
        va += __shfl_xor(va, 2);
        va += __shfl_xor(va, 4);
        va += __shfl_xor(va, 8);
        if (lane == 0) vout[node] = fmaxf(va + bg2[128], 0.f);
    }
}

extern "C" void kernel_launch(void* const* d_in, const int* in_sizes, int n_in,
                              void* d_out, int out_size, void* d_ws, size_t ws_size,
                              hipStream_t stream)
{
    const float* x      = (const float*)d_in[0];
    const float* rw1    = (const float*)d_in[1];
    const float* action = (const float*)d_in[2];
    const float* noise  = (const float*)d_in[3];
    const int*   eidx   = (const int*)d_in[4];
    const float* W1     = (const float*)d_in[5];
    const float* b1     = (const float*)d_in[6];
    const float* Wg1    = (const float*)d_in[7];
    const float* bg1    = (const float*)d_in[8];
    const float* Whv    = (const float*)d_in[9];
    const float* bhv    = (const float*)d_in[10];
    const float* Wg2    = (const float*)d_in[11];
    const float* bg2    = (const float*)d_in[12];
    const int* src = eidx;
    const int* dst = eidx + NE;

    // Regions (u16 units), 12.8M each:
    // R0: edge staging (6.4MB) -> tmp bf16 (ld 256)   R1: h -> hidden (ld 128)
    // R2: x3a (ld 256)                                R3: aggcat -> agghid (ld 128)
    ushort* R0 = (ushort*)d_ws;
    ushort* R1 = R0 + 12800000;
    ushort* R2 = R1 + 12800000;
    ushort* R3 = R2 + 12800000;
    unsigned* staging = (unsigned*)R0;           // NBUCK*CAP u32 = 6.4MB, dies before gemm3
    float* dis  = (float*)(R3 + 12800000);
    int* cnt    = (int*)(dis + NN);
    int* rowptr = cnt + NN;
    ushort* esrc = (ushort*)(rowptr + NN + 4);   // u16 src ids
    int* bsums  = (int*)(esrc + NE);
    ushort* Wt1  = (ushort*)(bsums + 128); // [128][256]
    ushort* Wtg1 = Wt1 + 128 * 256;        // [256][160]
    ushort* Whvt = Wtg1 + 256 * 160;       // [256][256]
    ushort* Wg2t = Whvt + 256 * 256;       // [128][128]
    float* wval  = (float*)(Wg2t + 128 * 128);   // [128]
    float2* aggra = (float2*)(wval + 128);       // [NN]
    int* bcur   = (int*)(aggra + NN);            // [NBUCK]

    const int T = 256;
    const int gemmRows = (NN + 127) / 128;   // 391
    const int aggBlocks = (NN + 3) / 4;      // one wave per node
    const int scanBlocks = (NN + 511) / 512; // 98

    // ---- prep: weight transposes ----
    transpose_all<<<609, T, 0, stream>>>(W1, Wg1, Whv, Wg2, Wt1, Wtg1, Whvt, Wg2t, wval);

    // ---- bucketed CSR build ----
    hipMemsetAsync(bcur, 0, NBUCK * sizeof(int), stream);
    bucket_edges<<<(NE + 8191) / 8192, T, 0, stream>>>(src, dst, bcur, staging, NE);
    hist_bucket<<<NBUCK, 128, 0, stream>>>(staging, bcur, cnt, NN);
    scan_block_sums<<<scanBlocks, T, 0, stream>>>(cnt, bsums, NN);
    scan_small<<<1, T, 0, stream>>>(bsums, scanBlocks);
    scan_write<<<scanBlocks, T, 0, stream>>>(cnt, bsums, rowptr, dis, NN, NE);
    sort_bucket<<<NBUCK, 128, 0, stream>>>(staging, bcur, rowptr, esrc);

    // ---- gemm1: relu(x@W1+b1) -> h bf16 (R1, ld 128); A = f32 x ----
    gemm_mfma<1, 256, 128, false><<<gemmRows, 512, 0, stream>>>(
        x, 256, NN, nullptr, Wt1, b1, R1, 128);

    // ---- agg1 on h -> aggcat (R3, ld 128) + fused rw/action -> aggra ----
    agg128<true, false><<<aggBlocks, T, 0, stream>>>(
        R1, R3, rowptr, esrc, dis, NN, rw1, action, aggra, nullptr, nullptr, nullptr);

    // ---- gemm2: relu([aggcat|aggra]@Wg1 + bg1) -> x3a bf16 (R2, ld 256) ----
    gemm_mfma<2, 160, 256, false><<<gemmRows, 512, 0, stream>>>(
        R3, 128, NN, aggra, Wtg1, bg1, R2, 256);

    // ---- gemm3: relu(x3a@Whv+bhv) -> tmp bf16 (R0, ld 256) ----
    gemm_mfma<0, 256, 256, false><<<gemmRows, 512, 0, stream>>>(
        R2, 256, NN, nullptr, Whvt, bhv, R0, 256);

    // ---- hidden (f32 math) -> bf16 (R1, ld 128) ----
    hidden_k<<<(NN * 32 + T - 1) / T, T, 0, stream>>>(R0, noise, R1, NN * 32);

    // ---- agg2 on hidden -> agghid (R3, ld 128) + fused value head ----
    agg128<false, true><<<aggBlocks, T, 0, stream>>>(
        R1, R3, rowptr, esrc, dis, NN, nullptr, nullptr, nullptr,
        wval, bg2, (float*)d_out + (size_t)NN * 128);

    // ---- gemm4: relu(agghid@Wg2 + bg2) cols 0..127 -> d_out f32 ld 128 ----
    gemm_mfma<0, 128, 128, true><<<gemmRows, 512, 0, stream>>>(
        R3, 128, NN, nullptr, Wg2t, bg2, d_out, 128);
}

// Round 9
// 214.003 us; speedup vs baseline: 22.3629x; 1.0390x over previous
//
#include <hip/hip_runtime.h>

static constexpr int NN = 50000;   // nodes
static constexpr int NE = 800000;  // edges
static constexpr int NBUCK = (NN + 127) / 128;  // 391 buckets (dst >> 7)
static constexpr int CAP = 4096;   // staging capacity per bucket (avg 2046, max ~2350)

typedef __attribute__((ext_vector_type(8))) short bf16x8;
typedef __attribute__((ext_vector_type(4))) float f32x4;

__device__ __forceinline__ float bf2f(ushort u) {
    union { unsigned int i; float f; } c; c.i = ((unsigned int)u) << 16; return c.f;
}
__device__ __forceinline__ ushort f2bf(float f) {
    union { float f; unsigned int i; } c; c.f = f;
    unsigned int x = c.i;
    return (ushort)((x + 0x7FFFu + ((x >> 16) & 1u)) >> 16);
}
__device__ __forceinline__ int packbf(float a, float b) {
    return (int)f2bf(a) | ((int)f2bf(b) << 16);
}

// ---------------- bucketed CSR build ----------------
// Phase A: partition edges into 391 dst-buckets; 2048 edges/block for parallelism.
__global__ __launch_bounds__(256) void bucket_edges(
    const int* __restrict__ src, const int* __restrict__ dst,
    int* __restrict__ bcur, unsigned* __restrict__ staging, int e)
{
    __shared__ int bins[NBUCK];
    __shared__ int gbase[NBUCK];
    __shared__ int cur[NBUCK];
    const int t = threadIdx.x;
    const int base = blockIdx.x * 2048;
    for (int i = t; i < NBUCK; i += 256) bins[i] = 0;
    __syncthreads();
    const int lim = min(2048, e - base);
    for (int i = t; i < lim; i += 256)
        atomicAdd(&bins[dst[base + i] >> 7], 1);
    __syncthreads();
    for (int i = t; i < NBUCK; i += 256) {
        cur[i] = 0;
        gbase[i] = bins[i] ? atomicAdd(&bcur[i], bins[i]) : 0;
    }
    __syncthreads();
    for (int i = t; i < lim; i += 256) {
        const int d = dst[base + i];
        const int b = d >> 7;
        const int r = atomicAdd(&cur[b], 1);
        staging[(size_t)b * CAP + gbase[b] + r] =
            ((unsigned)(d & 127) << 16) | (unsigned)src[base + i];
    }
}

// Phase B: per-bucket histogram -> cnt (plain stores, no global atomics)
__global__ __launch_bounds__(128) void hist_bucket(
    const unsigned* __restrict__ staging, const int* __restrict__ bcur,
    int* __restrict__ cnt, int n)
{
    __shared__ int bins[128];
    const int b = blockIdx.x;
    const int t = threadIdx.x;
    bins[t] = 0;
    __syncthreads();
    const int m = bcur[b];
    const unsigned* sp = staging + (size_t)b * CAP;
    for (int i = t; i < m; i += 128) atomicAdd(&bins[sp[i] >> 16], 1);
    __syncthreads();
    const int node = (b << 7) + t;
    if (node < n) cnt[node] = bins[t];
}

__global__ __launch_bounds__(256) void scan_block_sums(
    const int* __restrict__ cnt, int* __restrict__ blockSums, int n)
{
    __shared__ int sdata[256];
    const int base = blockIdx.x * 512;
    const int t = threadIdx.x;
    const int i0 = base + t * 2;
    int v = 0;
    if (i0 < n) v += cnt[i0];
    if (i0 + 1 < n) v += cnt[i0 + 1];
    sdata[t] = v;
    __syncthreads();
#pragma unroll
    for (int off = 128; off > 0; off >>= 1) {
        if (t < off) sdata[t] += sdata[t + off];
        __syncthreads();
    }
    if (t == 0) blockSums[blockIdx.x] = sdata[0];
}

__global__ __launch_bounds__(256) void scan_small(int* blockSums, int nb) {
    __shared__ int sdata[256];
    const int t = threadIdx.x;
    sdata[t] = (t < nb) ? blockSums[t] : 0;
    __syncthreads();
#pragma unroll
    for (int off = 1; off < 256; off <<= 1) {
        const int v = (t >= off) ? sdata[t - off] : 0;
        __syncthreads();
        sdata[t] += v;
        __syncthreads();
    }
    if (t < nb) blockSums[t] = (t == 0) ? 0 : sdata[t - 1];
}

// writes rowptr + dis
__global__ __launch_bounds__(256) void scan_write(
    const int* __restrict__ cnt, const int* __restrict__ blockOffs,
    int* __restrict__ rowptr, float* __restrict__ dis, int n, int e)
{
    __shared__ int sdata[256];
    const int base = blockIdx.x * 512;
    const int t = threadIdx.x;
    const int i0 = base + t * 2;
    const int c0 = (i0 < n) ? cnt[i0] : 0;
    const int c1 = (i0 + 1 < n) ? cnt[i0 + 1] : 0;
    sdata[t] = c0 + c1;
    __syncthreads();
#pragma unroll
    for (int off = 1; off < 256; off <<= 1) {
        const int v = (t >= off) ? sdata[t - off] : 0;
        __syncthreads();
        sdata[t] += v;
        __syncthreads();
    }
    const int pre = blockOffs[blockIdx.x] + ((t == 0) ? 0 : sdata[t - 1]);
    if (i0 < n)     { rowptr[i0] = pre;          dis[i0] = rsqrtf(1.0f + (float)c0); }
    if (i0 + 1 < n) { rowptr[i0 + 1] = pre + c0; dis[i0 + 1] = rsqrtf(1.0f + (float)c1); }
    if (blockIdx.x == 0 && t == 0) rowptr[n] = e;
}

// Phase C: sort within bucket via LDS counting sort; esrc written coalesced.
__global__ __launch_bounds__(128) void sort_bucket(
    const unsigned* __restrict__ staging, const int* __restrict__ bcur,
    const int* __restrict__ rowptr, ushort* __restrict__ esrc)
{
    __shared__ int bins[128];
    __shared__ int sdata[128];
    __shared__ ushort outb[CAP];
    const int b = blockIdx.x;
    const int t = threadIdx.x;
    bins[t] = 0;
    __syncthreads();
    const int m = bcur[b];
    const unsigned* sp = staging + (size_t)b * CAP;
    for (int i = t; i < m; i += 128) atomicAdd(&bins[sp[i] >> 16], 1);
    __syncthreads();
    const int v = bins[t];
    sdata[t] = v;
    __syncthreads();
#pragma unroll
    for (int off = 1; off < 128; off <<= 1) {
        const int u = (t >= off) ? sdata[t - off] : 0;
        __syncthreads();
        sdata[t] += u;
        __syncthreads();
    }
    bins[t] = sdata[t] - v;   // exclusive prefix -> cursor
    __syncthreads();
    for (int i = t; i < m; i += 128) {
        const unsigned p = sp[i];
        const int r = atomicAdd(&bins[p >> 16], 1);
        outb[r] = (ushort)(p & 0xffffu);
    }
    __syncthreads();
    const int ebase = rowptr[b << 7];
    for (int i = t; i < m; i += 128) esrc[ebase + i] = outb[i];
}

// ---------------- prep: weight transposes + value-head weights ----------------
__global__ void transpose_all(const float* __restrict__ W1, const float* __restrict__ Wg1,
                              const float* __restrict__ Whv, const float* __restrict__ Wg2,
                              ushort* __restrict__ Wt1, ushort* __restrict__ Wtg1,
                              ushort* __restrict__ Whvt, ushort* __restrict__ Wg2t,
                              float* __restrict__ wval)
{
    int idx = blockIdx.x * blockDim.x + threadIdx.x;
    if (idx < 128 * 256) {                 // Wt1 [128][256] <- W1 [256][128]
        const int n = idx >> 8, k = idx & 255;
        Wt1[idx] = f2bf(W1[k * 128 + n]);
        return;
    }
    idx -= 128 * 256;
    if (idx < 256 * 160) {                 // Wtg1 [256][160] <- Wg1 [130][256]
        const int n = idx / 160, k = idx - n * 160;
        Wtg1[idx] = (k < 130) ? f2bf(Wg1[k * 256 + n]) : (ushort)0;
        return;
    }
    idx -= 256 * 160;
    if (idx < 256 * 256) {                 // Whvt [256][256] <- Whv [256][256]
        const int n = idx >> 8, k = idx & 255;
        Whvt[idx] = f2bf(Whv[k * 256 + n]);
        return;
    }
    idx -= 256 * 256;
    if (idx < 128 * 128) {                 // Wg2t [128][128] <- Wg2 [128][129] cols 0..127
        const int n = idx >> 7, k = idx & 127;
        Wg2t[idx] = f2bf(Wg2[k * 129 + n]);
        return;
    }
    idx -= 128 * 128;
    if (idx < 128) wval[idx] = Wg2[idx * 129 + 128];   // value column, f32
}

// ---------------- bf16 MFMA GEMM (512 thr, tile 128 x NB, K-sliced W) --------
template<int AMODE, int K, int NB, bool OUTF32>
__global__ __launch_bounds__(512) void gemm_mfma(
    const void* __restrict__ Aptr, int lda, int M,
    const float2* __restrict__ aggra,
    const ushort* __restrict__ Wt,
    const float* __restrict__ bias,
    void* __restrict__ Cout, int ldc)
{
    constexpr int NK = K / 32;
    constexpr int CF = NB / 64;        // col frags per wave (2 or 4)
    __shared__ ushort A_s[2][128 * 40];
    __shared__ ushort W_s[2][NB * 40];

    const int tid  = threadIdx.x;
    const int row0 = blockIdx.x * 128;
    const int lane = tid & 63;
    const int wid  = tid >> 6;
    const int wr = wid >> 2;
    const int wc = wid & 3;
    const int lr = lane & 15;
    const int kg = lane >> 4;

    const int sr = tid >> 2;
    const int sc = (tid & 3) * 8;
    const bool rok = (row0 + sr) < M;
    const ushort* Agu = (const ushort*)Aptr + (size_t)(row0 + sr) * lda + sc;
    const float*  Agf = (const float*)Aptr + (size_t)(row0 + sr) * lda + sc;
    const ushort* Wg0 = Wt + (size_t)sr * K + sc;
    const ushort* Wg1p = Wt + (size_t)(sr + 128) * K + sc;

    int4 sa = make_int4(0,0,0,0), sw0 = sa, sw1 = sa;
    auto load_A = [&](int kk) {
        if (AMODE == 2 && kk == NK - 1) {
            sa = make_int4(0, 0, 0, 0);
            if (sc == 0 && rok) {
                const float2 ra = aggra[row0 + sr];
                sa.x = packbf(ra.x, ra.y);
            }
        } else if (AMODE == 1) {
            if (rok) {
                const float* p = Agf + kk * 32;
                const float4 f0 = *(const float4*)(p + 0);
                const float4 f1 = *(const float4*)(p + 4);
                sa.x = packbf(f0.x, f0.y); sa.y = packbf(f0.z, f0.w);
                sa.z = packbf(f1.x, f1.y); sa.w = packbf(f1.z, f1.w);
            } else sa = make_int4(0, 0, 0, 0);
        } else {
            sa = rok ? *(const int4*)(Agu + kk * 32) : make_int4(0, 0, 0, 0);
        }
    };
    auto load_W = [&](int kk) {
        sw0 = *(const int4*)(Wg0 + kk * 32);
        if constexpr (NB == 256) sw1 = *(const int4*)(Wg1p + kk * 32);
    };
    auto store_A = [&](int buf) { *(int4*)&A_s[buf][sr * 40 + sc] = sa; };
    auto store_W = [&](int buf) {
        *(int4*)&W_s[buf][sr * 40 + sc] = sw0;
        if constexpr (NB == 256) *(int4*)&W_s[buf][(sr + 128) * 40 + sc] = sw1;
    };

    load_A(0); load_W(0);
    store_A(0); store_W(0);

    f32x4 acc[4][CF];
#pragma unroll
    for (int m = 0; m < 4; ++m)
#pragma unroll
        for (int n = 0; n < CF; ++n) acc[m][n] = (f32x4){0.f, 0.f, 0.f, 0.f};

    const int abase = (wr * 64 + lr) * 40 + kg * 8;
    const int bbase = (wc * (NB / 4) + lr) * 40 + kg * 8;

    for (int kk = 0; kk < NK; ++kk) {
        if (kk + 1 < NK) { load_A(kk + 1); load_W(kk + 1); }
        __syncthreads();
        const ushort* Ab = A_s[kk & 1];
        const ushort* Wb = W_s[kk & 1];
        bf16x8 a[4], b[CF];
#pragma unroll
        for (int m = 0; m < 4; ++m) a[m] = *(const bf16x8*)&Ab[abase + m * 16 * 40];
#pragma unroll
        for (int n = 0; n < CF; ++n) b[n] = *(const bf16x8*)&Wb[bbase + n * 16 * 40];
#pragma unroll
        for (int m = 0; m < 4; ++m)
#pragma unroll
            for (int n = 0; n < CF; ++n)
                acc[m][n] = __builtin_amdgcn_mfma_f32_16x16x32_bf16(a[m], b[n], acc[m][n], 0, 0, 0);
        if (kk + 1 < NK) { store_A((kk + 1) & 1); store_W((kk + 1) & 1); }
    }

#pragma unroll
    for (int m = 0; m < 4; ++m) {
#pragma unroll
        for (int n = 0; n < CF; ++n) {
            const int c = wc * (NB / 4) + n * 16 + lr;
            const float bb = bias[c];
            const int r0 = row0 + wr * 64 + m * 16 + kg * 4;
#pragma unroll
            for (int r = 0; r < 4; ++r) {
                const int R = r0 + r;
                if (R >= M) continue;
                const float v = fmaxf(acc[m][n][r] + bb, 0.f);
                if (OUTF32) ((float*)Cout)[(size_t)R * ldc + c] = v;
                else        ((ushort*)Cout)[(size_t)R * ldc + c] = f2bf(v);
            }
        }
    }
}

// ---------------- glue ----------------
__global__ void hidden_k(const ushort* __restrict__ tmp, const float* __restrict__ noise,
                         ushort* __restrict__ hid, int n32) {
    int i = blockIdx.x * blockDim.x + threadIdx.x;
    if (i >= n32) return;
    const int row = i >> 5, c4 = (i & 31) * 4;
    const ushort4 mu = *(const ushort4*)(tmp + (size_t)row * 256 + c4);
    const ushort4 lg = *(const ushort4*)(tmp + (size_t)row * 256 + 128 + c4);
    const float4 nz = *(const float4*)(noise + (size_t)row * 128 + c4);
    ushort4 r;
    r.x = f2bf(bf2f(mu.x) + nz.x * expf(fminf(fmaxf(bf2f(lg.x), -5.f), 5.f)));
    r.y = f2bf(bf2f(mu.y) + nz.y * expf(fminf(fmaxf(bf2f(lg.y), -5.f), 5.f)));
    r.z = f2bf(bf2f(mu.z) + nz.z * expf(fminf(fmaxf(bf2f(lg.z), -5.f), 5.f)));
    r.w = f2bf(bf2f(mu.w) + nz.w * expf(fminf(fmaxf(bf2f(lg.w), -5.f), 5.f)));
    *(ushort4*)(hid + (size_t)row * 128 + c4) = r;
}

// ---------------- CSR gather aggregation, 128-col bf16 rows ----------------
// 16 lanes x int4 per edge row; 4 edge groups; 2 edges in flight per group.
// RA: fuse rw1/action aggregation (agg1). VAL: fuse value head (agg2).
template<bool RA, bool VAL>
__global__ __launch_bounds__(256) void agg128(
    const ushort* __restrict__ h, ushort* __restrict__ out,
    const int* __restrict__ rowptr, const ushort* __restrict__ esrc,
    const float* __restrict__ dis, int n,
    const float* __restrict__ rw1, const float* __restrict__ act,
    float2* __restrict__ aggra,
    const float* __restrict__ wval, const float* __restrict__ bg2,
    float* __restrict__ vout)
{
    const int node = (blockIdx.x * blockDim.x + threadIdx.x) >> 6;
    if (node >= n) return;
    const int lane = threadIdx.x & 63;
    const int g = lane >> 4;        // edge group 0..3
    const int sub = lane & 15;      // 8-col chunk
    const float dd = dis[node];

    float acc[8] = {0.f, 0.f, 0.f, 0.f, 0.f, 0.f, 0.f, 0.f};
    float ra_a = 0.f, ra_b = 0.f;
    if (g == 0) {   // self loop, counted once
        const int4 v = *(const int4*)(h + (size_t)node * 128 + sub * 8);
        const float d2 = dd * dd;
        acc[0] = bf2f((ushort)(v.x & 0xffff)) * d2;
        acc[1] = bf2f((ushort)((unsigned)v.x >> 16)) * d2;
        acc[2] = bf2f((ushort)(v.y & 0xffff)) * d2;
        acc[3] = bf2f((ushort)((unsigned)v.y >> 16)) * d2;
        acc[4] = bf2f((ushort)(v.z & 0xffff)) * d2;
        acc[5] = bf2f((ushort)((unsigned)v.z >> 16)) * d2;
        acc[6] = bf2f((ushort)(v.w & 0xffff)) * d2;
        acc[7] = bf2f((ushort)((unsigned)v.w >> 16)) * d2;
        if (RA && sub == 0) { ra_a = rw1[node] * d2; ra_b = act[node] * d2; }
    }
    const int e = rowptr[node + 1];
    int j = rowptr[node] + g;
    // 2 edges in flight per iteration (j, j+4)
    for (; j + 4 < e; j += 8) {
        const int s0 = (int)esrc[j];
        const int s1 = (int)esrc[j + 4];
        const float n0 = dis[s0] * dd;
        const float n1 = dis[s1] * dd;
        const int4 v0 = *(const int4*)(h + (size_t)s0 * 128 + sub * 8);
        const int4 v1 = *(const int4*)(h + (size_t)s1 * 128 + sub * 8);
        acc[0] += bf2f((ushort)(v0.x & 0xffff)) * n0 + bf2f((ushort)(v1.x & 0xffff)) * n1;
        acc[1] += bf2f((ushort)((unsigned)v0.x >> 16)) * n0 + bf2f((ushort)((unsigned)v1.x >> 16)) * n1;
        acc[2] += bf2f((ushort)(v0.y & 0xffff)) * n0 + bf2f((ushort)(v1.y & 0xffff)) * n1;
        acc[3] += bf2f((ushort)((unsigned)v0.y >> 16)) * n0 + bf2f((ushort)((unsigned)v1.y >> 16)) * n1;
        acc[4] += bf2f((ushort)(v0.z & 0xffff)) * n0 + bf2f((ushort)(v1.z & 0xffff)) * n1;
        acc[5] += bf2f((ushort)((unsigned)v0.z >> 16)) * n0 + bf2f((ushort)((unsigned)v1.z >> 16)) * n1;
        acc[6] += bf2f((ushort)(v0.w & 0xffff)) * n0 + bf2f((ushort)(v1.w & 0xffff)) * n1;
        acc[7] += bf2f((ushort)((unsigned)v0.w >> 16)) * n0 + bf2f((ushort)((unsigned)v1.w >> 16)) * n1;
        if (RA && sub == 0) {
            ra_a += rw1[s0] * n0 + rw1[s1] * n1;
            ra_b += act[s0] * n0 + act[s1] * n1;
        }
    }
    if (j < e) {
        const int s0 = (int)esrc[j];
        const float n0 = dis[s0] * dd;
        const int4 v0 = *(const int4*)(h + (size_t)s0 * 128 + sub * 8);
        acc[0] += bf2f((ushort)(v0.x & 0xffff)) * n0;
        acc[1] += bf2f((ushort)((unsigned)v0.x >> 16)) * n0;
        acc[2] += bf2f((ushort)(v0.y & 0xffff)) * n0;
        acc[3] += bf2f((ushort)((unsigned)v0.y >> 16)) * n0;
        acc[4] += bf2f((ushort)(v0.z & 0xffff)) * n0;
        acc[5] += bf2f((ushort)((unsigned)v0.z >> 16)) * n0;
        acc[6] += bf2f((ushort)(v0.w & 0xffff)) * n0;
        acc[7] += bf2f((ushort)((unsigned)v0.w >> 16)) * n0;
        if (RA && sub == 0) { ra_a += rw1[s0] * n0; ra_b += act[s0] * n0; }
    }
#pragma unroll
    for (int i = 0; i < 8; ++i) {
        acc[i] += __shfl_xor(acc[i], 16);
        acc[i] += __shfl_xor(acc[i], 32);
    }
    if (RA) {
        ra_a += __shfl_xor(ra_a, 16); ra_a += __shfl_xor(ra_a, 32);
        ra_b += __shfl_xor(ra_b, 16); ra_b += __shfl_xor(ra_b, 32);
        if (lane == 0) aggra[node] = make_float2(ra_a, ra_b);
    }
    if (g == 0) {
        int4 r;
        r.x = packbf(acc[0], acc[1]);
        r.y = packbf(acc[2], acc[3]);
        r.z = packbf(acc[4], acc[5]);
        r.w = packbf(acc[6], acc[7]);
        *(int4*)(out + (size_t)node * 128 + sub * 8) = r;
    }
    if (VAL) {   // fused value head on f32 accumulators
        float va = 0.f;
#pragma unroll
        for (int i = 0; i < 8; ++i) va += acc[i] * wval[sub * 8 + i];
        va += __shfl_xor(va, 1);
        va += __shfl_xor(va, 2);
        va += __shfl_xor(va, 4);
        va += __shfl_xor(va, 8);
        if (lane == 0) vout[node] = fmaxf(va + bg2[128], 0.f);
    }
}

extern "C" void kernel_launch(void* const* d_in, const int* in_sizes, int n_in,
                              void* d_out, int out_size, void* d_ws, size_t ws_size,
                              hipStream_t stream)
{
    const float* x      = (const float*)d_in[0];
    const float* rw1    = (const float*)d_in[1];
    const float* action = (const float*)d_in[2];
    const float* noise  = (const float*)d_in[3];
    const int*   eidx   = (const int*)d_in[4];
    const float* W1     = (const float*)d_in[5];
    const float* b1     = (const float*)d_in[6];
    const float* Wg1    = (const float*)d_in[7];
    const float* bg1    = (const float*)d_in[8];
    const float* Whv    = (const float*)d_in[9];
    const float* bhv    = (const float*)d_in[10];
    const float* Wg2    = (const float*)d_in[11];
    const float* bg2    = (const float*)d_in[12];
    const int* src = eidx;
    const int* dst = eidx + NE;

    // Regions (u16 units), 12.8M each:
    // R0: edge staging (6.4MB) -> tmp bf16 (ld 256)   R1: h -> hidden (ld 128)
    // R2: x3a (ld 256)                                R3: aggcat -> agghid (ld 128)
    ushort* R0 = (ushort*)d_ws;
    ushort* R1 = R0 + 12800000;
    ushort* R2 = R1 + 12800000;
    ushort* R3 = R2 + 12800000;
    unsigned* staging = (unsigned*)R0;           // NBUCK*CAP u32 = 6.4MB, dies before gemm3
    float* dis  = (float*)(R3 + 12800000);
    int* cnt    = (int*)(dis + NN);
    int* rowptr = cnt + NN;
    ushort* esrc = (ushort*)(rowptr + NN + 4);   // u16 src ids
    int* bsums  = (int*)(esrc + NE);
    ushort* Wt1  = (ushort*)(bsums + 128); // [128][256]
    ushort* Wtg1 = Wt1 + 128 * 256;        // [256][160]
    ushort* Whvt = Wtg1 + 256 * 160;       // [256][256]
    ushort* Wg2t = Whvt + 256 * 256;       // [128][128]
    float* wval  = (float*)(Wg2t + 128 * 128);   // [128]
    float2* aggra = (float2*)(wval + 128);       // [NN]
    int* bcur   = (int*)(aggra + NN);            // [NBUCK]

    const int T = 256;
    const int gemmRows = (NN + 127) / 128;   // 391
    const int aggBlocks = (NN + 3) / 4;      // one wave per node
    const int scanBlocks = (NN + 511) / 512; // 98

    // ---- prep: weight transposes ----
    transpose_all<<<609, T, 0, stream>>>(W1, Wg1, Whv, Wg2, Wt1, Wtg1, Whvt, Wg2t, wval);

    // ---- bucketed CSR build ----
    hipMemsetAsync(bcur, 0, NBUCK * sizeof(int), stream);
    bucket_edges<<<(NE + 2047) / 2048, T, 0, stream>>>(src, dst, bcur, staging, NE);
    hist_bucket<<<NBUCK, 128, 0, stream>>>(staging, bcur, cnt, NN);
    scan_block_sums<<<scanBlocks, T, 0, stream>>>(cnt, bsums, NN);
    scan_small<<<1, T, 0, stream>>>(bsums, scanBlocks);
    scan_write<<<scanBlocks, T, 0, stream>>>(cnt, bsums, rowptr, dis, NN, NE);
    sort_bucket<<<NBUCK, 128, 0, stream>>>(staging, bcur, rowptr, esrc);

    // ---- gemm1: relu(x@W1+b1) -> h bf16 (R1, ld 128); A = f32 x ----
    gemm_mfma<1, 256, 128, false><<<gemmRows, 512, 0, stream>>>(
        x, 256, NN, nullptr, Wt1, b1, R1, 128);

    // ---- agg1 on h -> aggcat (R3, ld 128) + fused rw/action -> aggra ----
    agg128<true, false><<<aggBlocks, T, 0, stream>>>(
        R1, R3, rowptr, esrc, dis, NN, rw1, action, aggra, nullptr, nullptr, nullptr);

    // ---- gemm2: relu([aggcat|aggra]@Wg1 + bg1) -> x3a bf16 (R2, ld 256) ----
    gemm_mfma<2, 160, 256, false><<<gemmRows, 512, 0, stream>>>(
        R3, 128, NN, aggra, Wtg1, bg1, R2, 256);

    // ---- gemm3: relu(x3a@Whv+bhv) -> tmp bf16 (R0, ld 256) ----
    gemm_mfma<0, 256, 256, false><<<gemmRows, 512, 0, stream>>>(
        R2, 256, NN, nullptr, Whvt, bhv, R0, 256);

    // ---- hidden (f32 math) -> bf16 (R1, ld 128) ----
    hidden_k<<<(NN * 32 + T - 1) / T, T, 0, stream>>>(R0, noise, R1, NN * 32);

    // ---- agg2 on hidden -> agghid (R3, ld 128) + fused value head ----
    agg128<false, true><<<aggBlocks, T, 0, stream>>>(
        R1, R3, rowptr, esrc, dis, NN, nullptr, nullptr, nullptr,
        wval, bg2, (float*)d_out + (size_t)NN * 128);

    // ---- gemm4: relu(agghid@Wg2 + bg2) cols 0..127 -> d_out f32 ld 128 ----
    gemm_mfma<0, 128, 128, true><<<gemmRows, 512, 0, stream>>>(
        R3, 128, NN, nullptr, Wg2t, bg2, d_out, 128);
}